// Round 1
// baseline (4490.306 us; speedup 1.0000x reference)
//
#include <hip/hip_runtime.h>
#include <hip/hip_bf16.h>
#include <math.h>

// FFNN_encoder: fp32 baseline implementation.
// B=2, S=2048, FIN=64, D=1024, H=16, DH=128, AF=2048.
// Pipeline:
//  1) embed_ln: h0 = LN(relu(x@W_emb+b) + timing_signal, g0, beta0)
//  2) gemm x3:  q/k/v = h0 @ Wq/Wk/Wv + b      [4096 x 2048]
//  3) attn:     flash-style causal attention, scale = 1/sqrt(S)
//  4) gemm:     ao = ctx @ Wo + bo
//  5) resid_ln: h1 = LN(h0 + ao, g1, beta1)
//  6) gemm:     mid = relu(h1 @ W1 + b1)       [4096 x 4096]
//  7) gemm:     f2 = mid @ W2 + b2
//  8) resid_ln: out = LN(h1 + f2, g2, beta2)

#define D_MODEL 1024
#define NHEADS  16
#define DHEAD   128
#define ATTF    2048
#define FIN     64
#define LN_EPS  1e-3f

// ---------------------------------------------------------------------------
// block-wide 2-value sum reduction (256 threads = 4 waves)
__device__ __forceinline__ void block_reduce2(float& a, float& b, float* sbuf) {
#pragma unroll
  for (int off = 32; off > 0; off >>= 1) {
    a += __shfl_xor(a, off);
    b += __shfl_xor(b, off);
  }
  int lane = threadIdx.x & 63;
  int w    = threadIdx.x >> 6;
  if (lane == 0) { sbuf[w] = a; sbuf[4 + w] = b; }
  __syncthreads();
  a = sbuf[0] + sbuf[1] + sbuf[2] + sbuf[3];
  b = sbuf[4] + sbuf[5] + sbuf[6] + sbuf[7];
}

// ---------------------------------------------------------------------------
// Kernel 1: embedding dense(64->1024) + relu + timing signal + LayerNorm
// one block (256 threads) per (b,s) row
__global__ __launch_bounds__(256) void embed_ln_kernel(
    const float* __restrict__ x, const float* __restrict__ Wemb,
    const float* __restrict__ bemb, const float* __restrict__ g0,
    const float* __restrict__ beta0, float* __restrict__ h0, int S)
{
  __shared__ __align__(16) float xs[FIN];
  __shared__ float red[8];
  int row = blockIdx.x;           // b*S + s
  int s   = row % S;
  int tid = threadIdx.x;
  if (tid < FIN / 4)
    *(float4*)&xs[tid * 4] = *(const float4*)&x[(size_t)row * FIN + tid * 4];
  __syncthreads();

  float acc[4];
#pragma unroll
  for (int j = 0; j < 4; ++j) acc[j] = bemb[tid + 256 * j];
#pragma unroll 8
  for (int f = 0; f < FIN; ++f) {
    float xf = xs[f];
    const float* wrow = Wemb + (size_t)f * D_MODEL + tid;
#pragma unroll
    for (int j = 0; j < 4; ++j) acc[j] = fmaf(xf, wrow[256 * j], acc[j]);
  }

  // relu + timing signal. num_ts = 512; log_inc = ln(10000)/511
  const float log_inc = 0.0180241487920284f;
  float ps = (float)s;
  float val[4];
#pragma unroll
  for (int j = 0; j < 4; ++j) {
    int d = tid + 256 * j;
    float ts;
    if (d < 512) ts = sinf(ps * expf(-(float)d * log_inc));
    else         ts = cosf(ps * expf(-(float)(d - 512) * log_inc));
    val[j] = fmaxf(acc[j], 0.f) + ts;
  }

  float sum = 0.f, ss = 0.f;
#pragma unroll
  for (int j = 0; j < 4; ++j) { sum += val[j]; ss += val[j] * val[j]; }
  block_reduce2(sum, ss, red);
  float mu  = sum * (1.f / D_MODEL);
  float var = ss * (1.f / D_MODEL) - mu * mu;
  float inv = rsqrtf(var + LN_EPS);
#pragma unroll
  for (int j = 0; j < 4; ++j) {
    int d = tid + 256 * j;
    h0[(size_t)row * D_MODEL + d] = (val[j] - mu) * inv * g0[d] + beta0[d];
  }
}

// ---------------------------------------------------------------------------
// Kernel 2: generic fp32 GEMM  C[M,N] = act(A[M,K] @ W[K,N] + bias[N])
// 128x128 tile, BK=16, 256 threads, 8x8 micro-tile per thread
__global__ __launch_bounds__(256) void gemm_f32_kernel(
    const float* __restrict__ A, const float* __restrict__ W,
    const float* __restrict__ bias, float* __restrict__ C,
    int M, int N, int K, int relu)
{
  __shared__ float As[16][129];                 // [k][m], padded
  __shared__ __align__(16) float Bs[16][128];   // [k][n]
  int tid = threadIdx.x;
  int tx = tid & 15, ty = tid >> 4;
  int m0 = blockIdx.y * 128, n0 = blockIdx.x * 128;

  float acc[8][8];
#pragma unroll
  for (int i = 0; i < 8; ++i)
#pragma unroll
    for (int j = 0; j < 8; ++j) acc[i][j] = 0.f;

  int ar  = tid >> 2;            // 0..63
  int akq = (tid & 3) * 4;       // 0,4,8,12
  int bkr = tid >> 5;            // 0..7
  int bnq = (tid & 31) * 4;      // 0..124

  for (int kt = 0; kt < K; kt += 16) {
    float4 a0 = *(const float4*)&A[(size_t)(m0 + ar) * K + kt + akq];
    float4 a1 = *(const float4*)&A[(size_t)(m0 + ar + 64) * K + kt + akq];
    float4 b0 = *(const float4*)&W[(size_t)(kt + bkr) * N + n0 + bnq];
    float4 b1 = *(const float4*)&W[(size_t)(kt + bkr + 8) * N + n0 + bnq];
    __syncthreads();  // previous iteration's reads complete
    As[akq + 0][ar] = a0.x; As[akq + 1][ar] = a0.y;
    As[akq + 2][ar] = a0.z; As[akq + 3][ar] = a0.w;
    As[akq + 0][ar + 64] = a1.x; As[akq + 1][ar + 64] = a1.y;
    As[akq + 2][ar + 64] = a1.z; As[akq + 3][ar + 64] = a1.w;
    *(float4*)&Bs[bkr][bnq]     = b0;
    *(float4*)&Bs[bkr + 8][bnq] = b1;
    __syncthreads();
#pragma unroll
    for (int kk = 0; kk < 16; ++kk) {
      float a[8];
#pragma unroll
      for (int i = 0; i < 8; ++i) a[i] = As[kk][ty * 8 + i];
      float4 t0 = *(const float4*)&Bs[kk][tx * 8];
      float4 t1 = *(const float4*)&Bs[kk][tx * 8 + 4];
      float bb[8] = {t0.x, t0.y, t0.z, t0.w, t1.x, t1.y, t1.z, t1.w};
#pragma unroll
      for (int i = 0; i < 8; ++i)
#pragma unroll
        for (int j = 0; j < 8; ++j)
          acc[i][j] = fmaf(a[i], bb[j], acc[i][j]);
    }
  }

#pragma unroll
  for (int i = 0; i < 8; ++i) {
    int m = m0 + ty * 8 + i;
#pragma unroll
    for (int j4 = 0; j4 < 2; ++j4) {
      int n = n0 + tx * 8 + j4 * 4;
      float4 o;
      o.x = acc[i][j4 * 4 + 0] + bias[n + 0];
      o.y = acc[i][j4 * 4 + 1] + bias[n + 1];
      o.z = acc[i][j4 * 4 + 2] + bias[n + 2];
      o.w = acc[i][j4 * 4 + 3] + bias[n + 3];
      if (relu) {
        o.x = fmaxf(o.x, 0.f); o.y = fmaxf(o.y, 0.f);
        o.z = fmaxf(o.z, 0.f); o.w = fmaxf(o.w, 0.f);
      }
      *(float4*)&C[(size_t)m * N + n] = o;
    }
  }
}

// ---------------------------------------------------------------------------
// Kernel 3: causal flash attention, scale = 1/sqrt(S).
// grid = (S/64, B*H). 256 threads = 4 waves; wave w owns q rows [qb+16w, qb+16w+16).
// lane layout: rl = lane>>2 (row), g = lane&3 (32-dim chunk of DH=128).
__global__ __launch_bounds__(256) void attn_causal_kernel(
    const float* __restrict__ Q, const float* __restrict__ Kb,
    const float* __restrict__ Vb, float* __restrict__ O, int S)
{
  const float SCALE = rsqrtf((float)S);
  int bh = blockIdx.y;
  int b = bh >> 4, h = bh & 15;
  int qb = blockIdx.x * 64;
  int tid = threadIdx.x;
  int w = tid >> 6, lane = tid & 63;
  int rl = lane >> 2, g = lane & 3;
  int qrow = qb + w * 16 + rl;
  size_t base = ((size_t)b * S * NHEADS + (size_t)h) * DHEAD;  // + s*H*DH

  float qreg[32];
  {
    const float* qp = Q + base + (size_t)qrow * (NHEADS * DHEAD) + g * 32;
#pragma unroll
    for (int i = 0; i < 8; ++i) {
      float4 v = *(const float4*)(qp + i * 4);
      qreg[i * 4 + 0] = v.x; qreg[i * 4 + 1] = v.y;
      qreg[i * 4 + 2] = v.z; qreg[i * 4 + 3] = v.w;
    }
  }
  float acc[32];
#pragma unroll
  for (int i = 0; i < 32; ++i) acc[i] = 0.f;
  float m = -3.0e38f, l = 0.f;

  __shared__ __align__(16) float Ks[32][128];
  __shared__ __align__(16) float Vs[32][128];
  int wave_max_row = qb + w * 16 + 15;

  for (int kt = 0; kt < qb + 64; kt += 32) {
    __syncthreads();  // previous tile fully consumed
#pragma unroll
    for (int i = 0; i < 4; ++i) {
      int idx = tid + i * 256;
      int kr = idx >> 5, d4 = (idx & 31) * 4;
      size_t goff = base + (size_t)(kt + kr) * (NHEADS * DHEAD) + d4;
      *(float4*)&Ks[kr][d4] = *(const float4*)(Kb + goff);
      *(float4*)&Vs[kr][d4] = *(const float4*)(Vb + goff);
    }
    __syncthreads();
    if (kt > wave_max_row) continue;  // barriers above still executed every iter

    float sc[32];
    float tmax = -3.0e38f;
#pragma unroll
    for (int j = 0; j < 32; ++j) {
      float p = 0.f;
#pragma unroll
      for (int d4 = 0; d4 < 8; ++d4) {
        float4 kv = *(const float4*)&Ks[j][g * 32 + d4 * 4];
        p = fmaf(qreg[d4 * 4 + 0], kv.x, p);
        p = fmaf(qreg[d4 * 4 + 1], kv.y, p);
        p = fmaf(qreg[d4 * 4 + 2], kv.z, p);
        p = fmaf(qreg[d4 * 4 + 3], kv.w, p);
      }
      p += __shfl_xor(p, 1);
      p += __shfl_xor(p, 2);
      p *= SCALE;
      if (kt + j > qrow) p = -1.0e30f;   // causal mask
      sc[j] = p;
      tmax = fmaxf(tmax, p);
    }
    float mn = fmaxf(m, tmax);
    float scale_old = expf(m - mn);
    l *= scale_old;
#pragma unroll
    for (int d = 0; d < 32; ++d) acc[d] *= scale_old;
#pragma unroll
    for (int j = 0; j < 32; ++j) {
      float pj = expf(sc[j] - mn);
      l += pj;
#pragma unroll
      for (int d4 = 0; d4 < 8; ++d4) {
        float4 vv = *(const float4*)&Vs[j][g * 32 + d4 * 4];
        acc[d4 * 4 + 0] = fmaf(pj, vv.x, acc[d4 * 4 + 0]);
        acc[d4 * 4 + 1] = fmaf(pj, vv.y, acc[d4 * 4 + 1]);
        acc[d4 * 4 + 2] = fmaf(pj, vv.z, acc[d4 * 4 + 2]);
        acc[d4 * 4 + 3] = fmaf(pj, vv.w, acc[d4 * 4 + 3]);
      }
    }
    m = mn;
  }

  float invl = 1.f / l;
  float* op = O + base + (size_t)qrow * (NHEADS * DHEAD) + g * 32;
#pragma unroll
  for (int i = 0; i < 8; ++i) {
    float4 o;
    o.x = acc[i * 4 + 0] * invl; o.y = acc[i * 4 + 1] * invl;
    o.z = acc[i * 4 + 2] * invl; o.w = acc[i * 4 + 3] * invl;
    *(float4*)(op + i * 4) = o;
  }
}

// ---------------------------------------------------------------------------
// Kernel 4: out = LN(a + r, gamma, beta). one block per row of 1024.
__global__ __launch_bounds__(256) void resid_ln_kernel(
    const float* __restrict__ a, const float* __restrict__ r,
    const float* __restrict__ gamma, const float* __restrict__ beta,
    float* __restrict__ out)
{
  __shared__ float red[8];
  size_t row = blockIdx.x;
  int tid = threadIdx.x;
  float4 av = *(const float4*)&a[row * D_MODEL + tid * 4];
  float4 rv = *(const float4*)&r[row * D_MODEL + tid * 4];
  float val[4] = {av.x + rv.x, av.y + rv.y, av.z + rv.z, av.w + rv.w};
  float sum = val[0] + val[1] + val[2] + val[3];
  float ss  = val[0] * val[0] + val[1] * val[1] + val[2] * val[2] + val[3] * val[3];
  block_reduce2(sum, ss, red);
  float mu  = sum * (1.f / D_MODEL);
  float var = ss * (1.f / D_MODEL) - mu * mu;
  float inv = rsqrtf(var + LN_EPS);
  float4 gv = *(const float4*)&gamma[tid * 4];
  float4 bv = *(const float4*)&beta[tid * 4];
  float4 o;
  o.x = (val[0] - mu) * inv * gv.x + bv.x;
  o.y = (val[1] - mu) * inv * gv.y + bv.y;
  o.z = (val[2] - mu) * inv * gv.z + bv.z;
  o.w = (val[3] - mu) * inv * gv.w + bv.w;
  *(float4*)&out[row * D_MODEL + tid * 4] = o;
}

// ---------------------------------------------------------------------------
extern "C" void kernel_launch(void* const* d_in, const int* in_sizes, int n_in,
                              void* d_out, int out_size, void* d_ws, size_t ws_size,
                              hipStream_t stream) {
  const float* x     = (const float*)d_in[0];
  const float* W_emb = (const float*)d_in[1];
  const float* b_emb = (const float*)d_in[2];
  const float* g0    = (const float*)d_in[3];
  const float* beta0 = (const float*)d_in[4];
  const float* Wq    = (const float*)d_in[5];
  const float* bq    = (const float*)d_in[6];
  const float* Wk    = (const float*)d_in[7];
  const float* bk    = (const float*)d_in[8];
  const float* Wv    = (const float*)d_in[9];
  const float* bv    = (const float*)d_in[10];
  const float* Wo    = (const float*)d_in[11];
  const float* bo    = (const float*)d_in[12];
  const float* g1    = (const float*)d_in[13];
  const float* beta1 = (const float*)d_in[14];
  const float* W1    = (const float*)d_in[15];
  const float* b1    = (const float*)d_in[16];
  const float* W2    = (const float*)d_in[17];
  const float* b2    = (const float*)d_in[18];
  const float* g2    = (const float*)d_in[19];
  const float* beta2 = (const float*)d_in[20];
  float* out = (float*)d_out;
  float* ws  = (float*)d_ws;

  const int S  = 2048;
  const int BS = in_sizes[0] / FIN;       // B*S = 4096
  const int B  = BS / S;                  // 2

  // workspace layout (floats). mid reuses q+k, f2 reuses v.
  size_t o_h0  = 0;
  size_t o_q   = o_h0  + (size_t)BS * D_MODEL;
  size_t o_k   = o_q   + (size_t)BS * ATTF;
  size_t o_v   = o_k   + (size_t)BS * ATTF;
  size_t o_ctx = o_v   + (size_t)BS * ATTF;
  size_t o_ao  = o_ctx + (size_t)BS * ATTF;
  size_t o_h1  = o_ao  + (size_t)BS * D_MODEL;
  size_t o_mid = o_q;    // 16.8M floats (= q+k region), live only in FFN phase
  size_t o_f2  = o_v;    // live only in FFN phase

  // 1) embed + timing + LN0
  embed_ln_kernel<<<BS, 256, 0, stream>>>(x, W_emb, b_emb, g0, beta0, ws + o_h0, S);

  // 2) q, k, v projections
  gemm_f32_kernel<<<dim3(ATTF / 128, BS / 128), 256, 0, stream>>>(
      ws + o_h0, Wq, bq, ws + o_q, BS, ATTF, D_MODEL, 0);
  gemm_f32_kernel<<<dim3(ATTF / 128, BS / 128), 256, 0, stream>>>(
      ws + o_h0, Wk, bk, ws + o_k, BS, ATTF, D_MODEL, 0);
  gemm_f32_kernel<<<dim3(ATTF / 128, BS / 128), 256, 0, stream>>>(
      ws + o_h0, Wv, bv, ws + o_v, BS, ATTF, D_MODEL, 0);

  // 3) causal attention
  attn_causal_kernel<<<dim3(S / 64, B * NHEADS), 256, 0, stream>>>(
      ws + o_q, ws + o_k, ws + o_v, ws + o_ctx, S);

  // 4) output projection
  gemm_f32_kernel<<<dim3(D_MODEL / 128, BS / 128), 256, 0, stream>>>(
      ws + o_ctx, Wo, bo, ws + o_ao, BS, D_MODEL, ATTF, 0);

  // 5) h1 = LN(h0 + ao)
  resid_ln_kernel<<<BS, 256, 0, stream>>>(ws + o_h0, ws + o_ao, g1, beta1, ws + o_h1);

  // 6) FFN up (relu)
  gemm_f32_kernel<<<dim3(4 * D_MODEL / 128, BS / 128), 256, 0, stream>>>(
      ws + o_h1, W1, b1, ws + o_mid, BS, 4 * D_MODEL, D_MODEL, 1);

  // 7) FFN down
  gemm_f32_kernel<<<dim3(D_MODEL / 128, BS / 128), 256, 0, stream>>>(
      ws + o_mid, W2, b2, ws + o_f2, BS, D_MODEL, 4 * D_MODEL, 0);

  // 8) out = LN(h1 + f2)
  resid_ln_kernel<<<BS, 256, 0, stream>>>(ws + o_h1, ws + o_f2, g2, beta2, out);
}

// Round 3
// 3825.751 us; speedup vs baseline: 1.1737x; 1.1737x over previous
//
#include <hip/hip_runtime.h>
#include <hip/hip_bf16.h>
#include <math.h>

// FFNN_encoder, round 3.
// B=2, S=2048, FIN=64, D=1024, H=16, DH=128, AF=2048.
// Changes vs baseline:
//  - All 5 big GEMMs now run on MFMA (bf16 3-product split: hi*hi+hi*lo+lo*hi,
//    ~1e-5 rel err), m97-style 128x128 tile, BK=32, global_load_lds staging,
//    weights pre-transposed to [N][K] hi/lo per call.
//  - Attention: conflict-free interleaved LDS columns, 2 q-rows/lane,
//    heavy-tile-first dispatch; writes ctx directly as bf16 hi/lo.

#define D_MODEL 1024
#define NHEADS  16
#define DHEAD   128
#define ATTF    2048
#define FIN     64
#define LN_EPS  1e-3f

typedef __attribute__((ext_vector_type(8))) short short8;
typedef __attribute__((ext_vector_type(4))) float f32x4;

#define GLOAD_LDS(gp, lp) \
  __builtin_amdgcn_global_load_lds((const __attribute__((address_space(1))) void*)(gp), \
                                   (__attribute__((address_space(3))) void*)(lp), 16, 0, 0)

// bf16 RNE conversion (bit-level, finite values only)
__device__ __forceinline__ unsigned short f2bf(float f) {
  unsigned int x = __float_as_uint(f);
  return (unsigned short)((x + 0x7fffu + ((x >> 16) & 1u)) >> 16);
}
__device__ __forceinline__ float bf2f(unsigned short u) {
  return __uint_as_float(((unsigned int)u) << 16);
}
__device__ __forceinline__ void bfsplit(float f, unsigned short& hi, unsigned short& lo) {
  hi = f2bf(f);
  lo = f2bf(f - bf2f(hi));
}

// ---------------------------------------------------------------------------
__device__ __forceinline__ void block_reduce2(float& a, float& b, float* sbuf) {
#pragma unroll
  for (int off = 32; off > 0; off >>= 1) {
    a += __shfl_xor(a, off);
    b += __shfl_xor(b, off);
  }
  int lane = threadIdx.x & 63;
  int w    = threadIdx.x >> 6;
  if (lane == 0) { sbuf[w] = a; sbuf[4 + w] = b; }
  __syncthreads();
  a = sbuf[0] + sbuf[1] + sbuf[2] + sbuf[3];
  b = sbuf[4] + sbuf[5] + sbuf[6] + sbuf[7];
}

// ---------------------------------------------------------------------------
// Kernel: weight transpose + bf16 hi/lo split.  W[K][N] fp32 -> T[N][K] bf16 x2
__global__ __launch_bounds__(256) void transpose_split_kernel(
    const float* __restrict__ W, unsigned short* __restrict__ Thi,
    unsigned short* __restrict__ Tlo, int K, int N)
{
  __shared__ float ls[32][33];
  int n0 = blockIdx.x * 32, k0 = blockIdx.y * 32;
  int t = threadIdx.x;
  int kl = t >> 3, nl4 = (t & 7) * 4;
  float4 v = *(const float4*)&W[(size_t)(k0 + kl) * N + n0 + nl4];
  ls[kl][nl4 + 0] = v.x; ls[kl][nl4 + 1] = v.y;
  ls[kl][nl4 + 2] = v.z; ls[kl][nl4 + 3] = v.w;
  __syncthreads();
  int nl = t >> 3, kl4 = (t & 7) * 4;
  ushort4 h4, l4;
  unsigned short h, l;
  bfsplit(ls[kl4 + 0][nl], h, l); h4.x = h; l4.x = l;
  bfsplit(ls[kl4 + 1][nl], h, l); h4.y = h; l4.y = l;
  bfsplit(ls[kl4 + 2][nl], h, l); h4.z = h; l4.z = l;
  bfsplit(ls[kl4 + 3][nl], h, l); h4.w = h; l4.w = l;
  size_t o = (size_t)(n0 + nl) * K + k0 + kl4;
  *(ushort4*)&Thi[o] = h4;
  *(ushort4*)&Tlo[o] = l4;
}

// ---------------------------------------------------------------------------
// Kernel: embedding dense(64->1024) + relu + timing signal + LayerNorm.
// Writes h0 fp32 (for residual) and h0 hi/lo bf16 (for QKV GEMMs).
__global__ __launch_bounds__(256) void embed_ln_kernel(
    const float* __restrict__ x, const float* __restrict__ Wemb,
    const float* __restrict__ bemb, const float* __restrict__ g0,
    const float* __restrict__ beta0, float* __restrict__ h0,
    unsigned short* __restrict__ h0hi, unsigned short* __restrict__ h0lo, int S)
{
  __shared__ __align__(16) float xs[FIN];
  __shared__ float red[8];
  int row = blockIdx.x;
  int s   = row % S;
  int tid = threadIdx.x;
  if (tid < FIN / 4)
    *(float4*)&xs[tid * 4] = *(const float4*)&x[(size_t)row * FIN + tid * 4];
  __syncthreads();

  float acc[4];
#pragma unroll
  for (int j = 0; j < 4; ++j) acc[j] = bemb[tid + 256 * j];
#pragma unroll 8
  for (int f = 0; f < FIN; ++f) {
    float xf = xs[f];
    const float* wrow = Wemb + (size_t)f * D_MODEL + tid;
#pragma unroll
    for (int j = 0; j < 4; ++j) acc[j] = fmaf(xf, wrow[256 * j], acc[j]);
  }

  const float log_inc = 0.0180241487920284f;  // ln(10000)/511
  float ps = (float)s;
  float val[4];
#pragma unroll
  for (int j = 0; j < 4; ++j) {
    int d = tid + 256 * j;
    float ts;
    if (d < 512) ts = sinf(ps * expf(-(float)d * log_inc));
    else         ts = cosf(ps * expf(-(float)(d - 512) * log_inc));
    val[j] = fmaxf(acc[j], 0.f) + ts;
  }

  float sum = 0.f, ss = 0.f;
#pragma unroll
  for (int j = 0; j < 4; ++j) { sum += val[j]; ss += val[j] * val[j]; }
  block_reduce2(sum, ss, red);
  float mu  = sum * (1.f / D_MODEL);
  float var = ss * (1.f / D_MODEL) - mu * mu;
  float inv = rsqrtf(var + LN_EPS);
#pragma unroll
  for (int j = 0; j < 4; ++j) {
    int d = tid + 256 * j;
    float v = (val[j] - mu) * inv * g0[d] + beta0[d];
    size_t idx = (size_t)row * D_MODEL + d;
    h0[idx] = v;
    unsigned short h, l;
    bfsplit(v, h, l);
    h0hi[idx] = h; h0lo[idx] = l;
  }
}

// ---------------------------------------------------------------------------
// Kernel: split-bf16 MFMA GEMM.  C[M,N] = act(A[M,K] @ B^T[N,K] + bias)
// A given as hi/lo bf16 [M][K]; B given as hi/lo bf16 [N][K] (pre-transposed).
// 128x128 tile, BK=32, 4 waves (2x2), 4x4 frags of 16x16x32 per wave.
// out: split==0 -> fp32 C;  split==1 -> bf16 hi/lo (Chi/Clo).
__global__ __launch_bounds__(256) void gemm_bf16s_kernel(
    const unsigned short* __restrict__ Ahi, const unsigned short* __restrict__ Alo,
    const unsigned short* __restrict__ Bhi, const unsigned short* __restrict__ Blo,
    const float* __restrict__ bias, float* __restrict__ C,
    unsigned short* __restrict__ Chi, unsigned short* __restrict__ Clo,
    int M, int N, int K, int relu, int split)
{
  __shared__ unsigned short lds[4][128][32];   // Ahi, Alo, Bhi, Blo; 32 KiB
  int tid = threadIdx.x;
  int w = tid >> 6, lane = tid & 63;
  int m0 = blockIdx.y * 128, n0 = blockIdx.x * 128;
  int wm = (w >> 1) * 64, wn = (w & 1) * 64;
  int fl = lane & 15, fh = lane >> 4;          // frag col / k-group

  f32x4 acc[4][4];
#pragma unroll
  for (int i = 0; i < 4; ++i)
#pragma unroll
    for (int j = 0; j < 4; ++j)
#pragma unroll
      for (int r = 0; r < 4; ++r) acc[i][j][r] = 0.f;

  const unsigned short* gbase[4];
  gbase[0] = Ahi + (size_t)m0 * K;
  gbase[1] = Alo + (size_t)m0 * K;
  gbase[2] = Bhi + (size_t)n0 * K;
  gbase[3] = Blo + (size_t)n0 * K;
  int srow = w * 16 + (lane >> 2);   // staged row within 64-row round
  int scol = (lane & 3) * 8;         // element offset within 32-elem row

  for (int kt = 0; kt < K; kt += 32) {
    __syncthreads();                 // previous compute done
#pragma unroll
    for (int t = 0; t < 4; ++t) {
#pragma unroll
      for (int r = 0; r < 2; ++r) {
        const unsigned short* src = gbase[t] + (size_t)(r * 64 + srow) * K + kt + scol;
        GLOAD_LDS(src, &lds[t][r * 64 + w * 16][0]);
      }
    }
    __syncthreads();                 // staging drained (vmcnt0 before barrier)

    short8 ah[4], al[4];
#pragma unroll
    for (int i = 0; i < 4; ++i) {
      ah[i] = *(const short8*)&lds[0][wm + i * 16 + fl][fh * 8];
      al[i] = *(const short8*)&lds[1][wm + i * 16 + fl][fh * 8];
    }
#pragma unroll
    for (int j = 0; j < 4; ++j) {
      short8 bh = *(const short8*)&lds[2][wn + j * 16 + fl][fh * 8];
      short8 bl = *(const short8*)&lds[3][wn + j * 16 + fl][fh * 8];
#pragma unroll
      for (int i = 0; i < 4; ++i) {
        acc[i][j] = __builtin_amdgcn_mfma_f32_16x16x32_bf16(ah[i], bh, acc[i][j], 0, 0, 0);
        acc[i][j] = __builtin_amdgcn_mfma_f32_16x16x32_bf16(ah[i], bl, acc[i][j], 0, 0, 0);
        acc[i][j] = __builtin_amdgcn_mfma_f32_16x16x32_bf16(al[i], bh, acc[i][j], 0, 0, 0);
      }
    }
  }

  // epilogue: C/D layout col=lane&15, row=(lane>>4)*4+reg  [HW-verified]
#pragma unroll
  for (int j = 0; j < 4; ++j) {
    int gc = n0 + wn + j * 16 + fl;
    float bv = bias[gc];
#pragma unroll
    for (int i = 0; i < 4; ++i) {
      int gr = m0 + wm + i * 16 + fh * 4;
#pragma unroll
      for (int r = 0; r < 4; ++r) {
        float v = acc[i][j][r] + bv;
        if (relu) v = fmaxf(v, 0.f);
        size_t o = (size_t)(gr + r) * N + gc;
        if (split) {
          unsigned short h, l;
          bfsplit(v, h, l);
          Chi[o] = h; Clo[o] = l;
        } else {
          C[o] = v;
        }
      }
    }
  }
}

// ---------------------------------------------------------------------------
// Kernel: causal flash attention, scale = 1/sqrt(S).  fp32 in, bf16 hi/lo out.
// grid = (S/64, B*H), heavy q-tiles first. 4 waves; wave w: rows [qb+16w,+16).
// lane: rl=lane>>3 (row), g=lane&7 owns cols i*32+g*4 (16B spacing across the
// 8 lanes => banks 0..31, conflict-free). 2 q-rows/lane share K/V LDS reads.
__global__ __launch_bounds__(256) void attn_causal_kernel(
    const float* __restrict__ Q, const float* __restrict__ Kb,
    const float* __restrict__ Vb, unsigned short* __restrict__ Ohi,
    unsigned short* __restrict__ Olo, int S)
{
  const float SCALE = rsqrtf((float)S);
  const int RS = NHEADS * DHEAD;           // 2048
  int bh = blockIdx.y;
  int b = bh >> 4, h = bh & 15;
  int qb = ((int)gridDim.x - 1 - (int)blockIdx.x) * 64;
  int tid = threadIdx.x;
  int w = tid >> 6, lane = tid & 63;
  int rl = lane >> 3, g = lane & 7;
  size_t base = ((size_t)b * S * NHEADS + (size_t)h) * DHEAD;

  int qrow[2];
  qrow[0] = qb + w * 16 + rl;
  qrow[1] = qb + w * 16 + 8 + rl;

  float qreg[2][16], acc[2][16];
#pragma unroll
  for (int r = 0; r < 2; ++r) {
    const float* qp = Q + base + (size_t)qrow[r] * RS + g * 4;
#pragma unroll
    for (int i = 0; i < 4; ++i) {
      float4 v = *(const float4*)(qp + i * 32);
      qreg[r][i * 4 + 0] = v.x * SCALE; qreg[r][i * 4 + 1] = v.y * SCALE;
      qreg[r][i * 4 + 2] = v.z * SCALE; qreg[r][i * 4 + 3] = v.w * SCALE;
    }
#pragma unroll
    for (int e = 0; e < 16; ++e) acc[r][e] = 0.f;
  }
  float m[2] = {-3.0e38f, -3.0e38f}, l[2] = {0.f, 0.f};

  __shared__ __align__(16) float Ks[32][128];
  __shared__ __align__(16) float Vs[32][128];
  int wave_max = qb + w * 16 + 15;

  for (int kt = 0; kt < qb + 64; kt += 32) {
    __syncthreads();
#pragma unroll
    for (int i = 0; i < 4; ++i) {
      int idx = tid + i * 256;
      int kr = idx >> 5, d4 = (idx & 31) * 4;
      size_t goff = base + (size_t)(kt + kr) * RS + d4;
      *(float4*)&Ks[kr][d4] = *(const float4*)(Kb + goff);
      *(float4*)&Vs[kr][d4] = *(const float4*)(Vb + goff);
    }
    __syncthreads();

#pragma unroll
    for (int jh = 0; jh < 32; jh += 16) {
      if (kt + jh > wave_max) continue;   // no barriers inside

      float sc[2][16];
      float tmax[2] = {-3.0e38f, -3.0e38f};
#pragma unroll
      for (int j = 0; j < 16; ++j) {
        int kj = jh + j;
        float kv[16];
#pragma unroll
        for (int i = 0; i < 4; ++i) {
          float4 t = *(const float4*)&Ks[kj][i * 32 + g * 4];
          kv[i * 4 + 0] = t.x; kv[i * 4 + 1] = t.y;
          kv[i * 4 + 2] = t.z; kv[i * 4 + 3] = t.w;
        }
        float p0 = 0.f, p1 = 0.f;
#pragma unroll
        for (int e = 0; e < 16; ++e) {
          p0 = fmaf(qreg[0][e], kv[e], p0);
          p1 = fmaf(qreg[1][e], kv[e], p1);
        }
        p0 += __shfl_xor(p0, 1); p1 += __shfl_xor(p1, 1);
        p0 += __shfl_xor(p0, 2); p1 += __shfl_xor(p1, 2);
        p0 += __shfl_xor(p0, 4); p1 += __shfl_xor(p1, 4);
        int kcol = kt + kj;
        sc[0][j] = (kcol > qrow[0]) ? -3.0e38f : p0;
        sc[1][j] = (kcol > qrow[1]) ? -3.0e38f : p1;
        tmax[0] = fmaxf(tmax[0], sc[0][j]);
        tmax[1] = fmaxf(tmax[1], sc[1][j]);
      }
#pragma unroll
      for (int r = 0; r < 2; ++r) {
        float mn = fmaxf(m[r], tmax[r]);
        float so = expf(m[r] - mn);
        l[r] *= so;
#pragma unroll
        for (int e = 0; e < 16; ++e) acc[r][e] *= so;
        m[r] = mn;
      }
#pragma unroll
      for (int j = 0; j < 16; ++j) {
        int kj = jh + j;
        float p0 = expf(sc[0][j] - m[0]);
        float p1 = expf(sc[1][j] - m[1]);
        l[0] += p0; l[1] += p1;
#pragma unroll
        for (int i = 0; i < 4; ++i) {
          float4 t = *(const float4*)&Vs[kj][i * 32 + g * 4];
          acc[0][i * 4 + 0] = fmaf(p0, t.x, acc[0][i * 4 + 0]);
          acc[0][i * 4 + 1] = fmaf(p0, t.y, acc[0][i * 4 + 1]);
          acc[0][i * 4 + 2] = fmaf(p0, t.z, acc[0][i * 4 + 2]);
          acc[0][i * 4 + 3] = fmaf(p0, t.w, acc[0][i * 4 + 3]);
          acc[1][i * 4 + 0] = fmaf(p1, t.x, acc[1][i * 4 + 0]);
          acc[1][i * 4 + 1] = fmaf(p1, t.y, acc[1][i * 4 + 1]);
          acc[1][i * 4 + 2] = fmaf(p1, t.z, acc[1][i * 4 + 2]);
          acc[1][i * 4 + 3] = fmaf(p1, t.w, acc[1][i * 4 + 3]);
        }
      }
    }
  }

#pragma unroll
  for (int r = 0; r < 2; ++r) {
    float inv = 1.f / l[r];
    size_t ro = base + (size_t)qrow[r] * RS + g * 4;
#pragma unroll
    for (int i = 0; i < 4; ++i) {
      ushort4 h4, l4;
      unsigned short hh, ll;
      bfsplit(acc[r][i * 4 + 0] * inv, hh, ll); h4.x = hh; l4.x = ll;
      bfsplit(acc[r][i * 4 + 1] * inv, hh, ll); h4.y = hh; l4.y = ll;
      bfsplit(acc[r][i * 4 + 2] * inv, hh, ll); h4.z = hh; l4.z = ll;
      bfsplit(acc[r][i * 4 + 3] * inv, hh, ll); h4.w = hh; l4.w = ll;
      *(ushort4*)&Ohi[ro + i * 32] = h4;
      *(ushort4*)&Olo[ro + i * 32] = l4;
    }
  }
}

// ---------------------------------------------------------------------------
// Kernel: out = LN(a + r); optionally also bf16 hi/lo split of out.
__global__ __launch_bounds__(256) void resid_ln_kernel(
    const float* __restrict__ a, const float* __restrict__ r,
    const float* __restrict__ gamma, const float* __restrict__ beta,
    float* __restrict__ out, unsigned short* __restrict__ ohi,
    unsigned short* __restrict__ olo)
{
  __shared__ float red[8];
  size_t row = blockIdx.x;
  int tid = threadIdx.x;
  float4 av = *(const float4*)&a[row * D_MODEL + tid * 4];
  float4 rv = *(const float4*)&r[row * D_MODEL + tid * 4];
  float val[4] = {av.x + rv.x, av.y + rv.y, av.z + rv.z, av.w + rv.w};
  float sum = val[0] + val[1] + val[2] + val[3];
  float ss  = val[0] * val[0] + val[1] * val[1] + val[2] * val[2] + val[3] * val[3];
  block_reduce2(sum, ss, red);
  float mu  = sum * (1.f / D_MODEL);
  float var = ss * (1.f / D_MODEL) - mu * mu;
  float inv = rsqrtf(var + LN_EPS);
  float4 gv = *(const float4*)&gamma[tid * 4];
  float4 bv = *(const float4*)&beta[tid * 4];
  float o[4];
  o[0] = (val[0] - mu) * inv * gv.x + bv.x;
  o[1] = (val[1] - mu) * inv * gv.y + bv.y;
  o[2] = (val[2] - mu) * inv * gv.z + bv.z;
  o[3] = (val[3] - mu) * inv * gv.w + bv.w;
  *(float4*)&out[row * D_MODEL + tid * 4] = *(float4*)o;
  if (ohi) {
    ushort4 h4, l4;
    unsigned short h, l;
    bfsplit(o[0], h, l); h4.x = h; l4.x = l;
    bfsplit(o[1], h, l); h4.y = h; l4.y = l;
    bfsplit(o[2], h, l); h4.z = h; l4.z = l;
    bfsplit(o[3], h, l); h4.w = h; l4.w = l;
    *(ushort4*)&ohi[row * D_MODEL + tid * 4] = h4;
    *(ushort4*)&olo[row * D_MODEL + tid * 4] = l4;
  }
}

// ---------------------------------------------------------------------------
extern "C" void kernel_launch(void* const* d_in, const int* in_sizes, int n_in,
                              void* d_out, int out_size, void* d_ws, size_t ws_size,
                              hipStream_t stream) {
  const float* x     = (const float*)d_in[0];
  const float* W_emb = (const float*)d_in[1];
  const float* b_emb = (const float*)d_in[2];
  const float* g0    = (const float*)d_in[3];
  const float* beta0 = (const float*)d_in[4];
  const float* Wq    = (const float*)d_in[5];
  const float* bq    = (const float*)d_in[6];
  const float* Wk    = (const float*)d_in[7];
  const float* bk    = (const float*)d_in[8];
  const float* Wv    = (const float*)d_in[9];
  const float* bv    = (const float*)d_in[10];
  const float* Wo    = (const float*)d_in[11];
  const float* bo    = (const float*)d_in[12];
  const float* g1    = (const float*)d_in[13];
  const float* beta1 = (const float*)d_in[14];
  const float* W1    = (const float*)d_in[15];
  const float* b1    = (const float*)d_in[16];
  const float* W2    = (const float*)d_in[17];
  const float* b2    = (const float*)d_in[18];
  const float* g2    = (const float*)d_in[19];
  const float* beta2 = (const float*)d_in[20];
  float* out = (float*)d_out;
  char* W = (char*)d_ws;

  const int S  = 2048;
  const int BS = in_sizes[0] / FIN;       // 4096
  const int B  = BS / S;                  // 2
  const size_t MB = 1024 * 1024;

  // workspace layout (byte offsets, 224 MB total; aliases noted)
  unsigned short* wqThi = (unsigned short*)(W + 0 * MB);
  unsigned short* wqTlo = (unsigned short*)(W + 4 * MB);
  unsigned short* wkThi = (unsigned short*)(W + 8 * MB);
  unsigned short* wkTlo = (unsigned short*)(W + 12 * MB);
  unsigned short* wvThi = (unsigned short*)(W + 16 * MB);
  unsigned short* wvTlo = (unsigned short*)(W + 20 * MB);
  unsigned short* woThi = (unsigned short*)(W + 24 * MB);
  unsigned short* woTlo = (unsigned short*)(W + 28 * MB);
  unsigned short* w1Thi = (unsigned short*)(W + 32 * MB);
  unsigned short* w1Tlo = (unsigned short*)(W + 40 * MB);
  unsigned short* w2Thi = (unsigned short*)(W + 48 * MB);
  unsigned short* w2Tlo = (unsigned short*)(W + 56 * MB);
  float*          h0f   = (float*)        (W + 64 * MB);
  unsigned short* h0hi  = (unsigned short*)(W + 80 * MB);
  unsigned short* h0lo  = (unsigned short*)(W + 88 * MB);
  float*          qf    = (float*)        (W + 96 * MB);
  float*          kf    = (float*)        (W + 128 * MB);
  float*          vf    = (float*)        (W + 160 * MB);
  unsigned short* ctxhi = (unsigned short*)(W + 192 * MB);
  unsigned short* ctxlo = (unsigned short*)(W + 208 * MB);
  float*          ao    = (float*)        (W + 96 * MB);   // alias q (dead)
  float*          h1f   = (float*)        (W + 128 * MB);  // alias k (dead)
  unsigned short* h1hi  = (unsigned short*)(W + 144 * MB);
  unsigned short* h1lo  = (unsigned short*)(W + 152 * MB);
  unsigned short* midhi = (unsigned short*)(W + 160 * MB); // alias v+ctx (dead)
  unsigned short* midlo = (unsigned short*)(W + 192 * MB);
  float*          f2    = (float*)        (W + 80 * MB);   // alias h0hi/lo (dead)

  // 0) weight transpose + split (per call; graph-safe)
  transpose_split_kernel<<<dim3(ATTF / 32, D_MODEL / 32), 256, 0, stream>>>(Wq, wqThi, wqTlo, D_MODEL, ATTF);
  transpose_split_kernel<<<dim3(ATTF / 32, D_MODEL / 32), 256, 0, stream>>>(Wk, wkThi, wkTlo, D_MODEL, ATTF);
  transpose_split_kernel<<<dim3(ATTF / 32, D_MODEL / 32), 256, 0, stream>>>(Wv, wvThi, wvTlo, D_MODEL, ATTF);
  transpose_split_kernel<<<dim3(D_MODEL / 32, ATTF / 32), 256, 0, stream>>>(Wo, woThi, woTlo, ATTF, D_MODEL);
  transpose_split_kernel<<<dim3(4 * D_MODEL / 32, D_MODEL / 32), 256, 0, stream>>>(W1, w1Thi, w1Tlo, D_MODEL, 4 * D_MODEL);
  transpose_split_kernel<<<dim3(D_MODEL / 32, 4 * D_MODEL / 32), 256, 0, stream>>>(W2, w2Thi, w2Tlo, 4 * D_MODEL, D_MODEL);

  // 1) embed + timing + LN0
  embed_ln_kernel<<<BS, 256, 0, stream>>>(x, W_emb, b_emb, g0, beta0, h0f, h0hi, h0lo, S);

  // 2) q, k, v projections (fp32 out)
  gemm_bf16s_kernel<<<dim3(ATTF / 128, BS / 128), 256, 0, stream>>>(
      h0hi, h0lo, wqThi, wqTlo, bq, qf, nullptr, nullptr, BS, ATTF, D_MODEL, 0, 0);
  gemm_bf16s_kernel<<<dim3(ATTF / 128, BS / 128), 256, 0, stream>>>(
      h0hi, h0lo, wkThi, wkTlo, bk, kf, nullptr, nullptr, BS, ATTF, D_MODEL, 0, 0);
  gemm_bf16s_kernel<<<dim3(ATTF / 128, BS / 128), 256, 0, stream>>>(
      h0hi, h0lo, wvThi, wvTlo, bv, vf, nullptr, nullptr, BS, ATTF, D_MODEL, 0, 0);

  // 3) causal attention -> ctx hi/lo
  attn_causal_kernel<<<dim3(S / 64, B * NHEADS), 256, 0, stream>>>(
      qf, kf, vf, ctxhi, ctxlo, S);

  // 4) output projection -> ao fp32
  gemm_bf16s_kernel<<<dim3(D_MODEL / 128, BS / 128), 256, 0, stream>>>(
      ctxhi, ctxlo, woThi, woTlo, bo, ao, nullptr, nullptr, BS, D_MODEL, ATTF, 0, 0);

  // 5) h1 = LN(h0 + ao), + hi/lo split
  resid_ln_kernel<<<BS, 256, 0, stream>>>(h0f, ao, g1, beta1, h1f, h1hi, h1lo);

  // 6) FFN up (relu) -> mid hi/lo
  gemm_bf16s_kernel<<<dim3(4 * D_MODEL / 128, BS / 128), 256, 0, stream>>>(
      h1hi, h1lo, w1Thi, w1Tlo, b1, nullptr, midhi, midlo, BS, 4 * D_MODEL, D_MODEL, 1, 1);

  // 7) FFN down -> f2 fp32
  gemm_bf16s_kernel<<<dim3(D_MODEL / 128, BS / 128), 256, 0, stream>>>(
      midhi, midlo, w2Thi, w2Tlo, b2, f2, nullptr, nullptr, BS, D_MODEL, 4 * D_MODEL, 0, 0);

  // 8) out = LN(h1 + f2)
  resid_ln_kernel<<<BS, 256, 0, stream>>>(h1f, f2, g2, beta2, out, nullptr, nullptr);
}

// Round 7
// 1387.360 us; speedup vs baseline: 3.2366x; 2.7576x over previous
//
#include <hip/hip_runtime.h>
#include <hip/hip_bf16.h>
#include <math.h>

// FFNN_encoder, round 7 (identical resubmit of R4-R6 — infra timeouts).
// B=2, S=2048, FIN=64, D=1024, H=16, DH=128, AF=2048.
// Attention on MFMA (split-bf16 QK^T and PV, flash-style, exp2 domain,
// per-wave P round-trip through padded LDS). QKV GEMMs emit head-major
// bf16 hi/lo directly; V^T produced by a small transpose kernel.

#define D_MODEL 1024
#define NHEADS  16
#define DHEAD   128
#define ATTF    2048
#define FIN     64
#define LN_EPS  1e-3f

typedef __attribute__((ext_vector_type(8))) short short8;
typedef __attribute__((ext_vector_type(4))) float f32x4;

#define GLOAD_LDS(gp, lp) \
  __builtin_amdgcn_global_load_lds((const __attribute__((address_space(1))) void*)(gp), \
                                   (__attribute__((address_space(3))) void*)(lp), 16, 0, 0)

// bf16 RNE conversion (bit-level, finite values only)
__device__ __forceinline__ unsigned short f2bf(float f) {
  unsigned int x = __float_as_uint(f);
  return (unsigned short)((x + 0x7fffu + ((x >> 16) & 1u)) >> 16);
}
__device__ __forceinline__ float bf2f(unsigned short u) {
  return __uint_as_float(((unsigned int)u) << 16);
}
__device__ __forceinline__ void bfsplit(float f, unsigned short& hi, unsigned short& lo) {
  hi = f2bf(f);
  lo = f2bf(f - bf2f(hi));
}

// ---------------------------------------------------------------------------
__device__ __forceinline__ void block_reduce2(float& a, float& b, float* sbuf) {
#pragma unroll
  for (int off = 32; off > 0; off >>= 1) {
    a += __shfl_xor(a, off);
    b += __shfl_xor(b, off);
  }
  int lane = threadIdx.x & 63;
  int w    = threadIdx.x >> 6;
  if (lane == 0) { sbuf[w] = a; sbuf[4 + w] = b; }
  __syncthreads();
  a = sbuf[0] + sbuf[1] + sbuf[2] + sbuf[3];
  b = sbuf[4] + sbuf[5] + sbuf[6] + sbuf[7];
}

// ---------------------------------------------------------------------------
// Weight transpose + bf16 hi/lo split.  W[K][N] fp32 -> T[N][K] bf16 x2
__global__ __launch_bounds__(256) void transpose_split_kernel(
    const float* __restrict__ W, unsigned short* __restrict__ Thi,
    unsigned short* __restrict__ Tlo, int K, int N)
{
  __shared__ float ls[32][33];
  int n0 = blockIdx.x * 32, k0 = blockIdx.y * 32;
  int t = threadIdx.x;
  int kl = t >> 3, nl4 = (t & 7) * 4;
  float4 v = *(const float4*)&W[(size_t)(k0 + kl) * N + n0 + nl4];
  ls[kl][nl4 + 0] = v.x; ls[kl][nl4 + 1] = v.y;
  ls[kl][nl4 + 2] = v.z; ls[kl][nl4 + 3] = v.w;
  __syncthreads();
  int nl = t >> 3, kl4 = (t & 7) * 4;
  ushort4 h4, l4;
  unsigned short h, l;
  bfsplit(ls[kl4 + 0][nl], h, l); h4.x = h; l4.x = l;
  bfsplit(ls[kl4 + 1][nl], h, l); h4.y = h; l4.y = l;
  bfsplit(ls[kl4 + 2][nl], h, l); h4.z = h; l4.z = l;
  bfsplit(ls[kl4 + 3][nl], h, l); h4.w = h; l4.w = l;
  size_t o = (size_t)(n0 + nl) * K + k0 + kl4;
  *(ushort4*)&Thi[o] = h4;
  *(ushort4*)&Tlo[o] = l4;
}

// ---------------------------------------------------------------------------
// V transpose per (b,h): V[(bh)][s][dh] -> VT[(bh)][dh][s], bf16 hi/lo
__global__ __launch_bounds__(256) void transpose_v_kernel(
    const unsigned short* __restrict__ Vhi, const unsigned short* __restrict__ Vlo,
    unsigned short* __restrict__ VThi, unsigned short* __restrict__ VTlo, int S)
{
  __shared__ unsigned short ls[32][36];
  int s0 = blockIdx.x * 32, d0 = blockIdx.y * 32;
  int bh = blockIdx.z;
  size_t base = (size_t)bh * S * DHEAD;
  int t = threadIdx.x;
  int sl = t >> 3, c4 = (t & 7) * 4;
#pragma unroll
  for (int buf = 0; buf < 2; ++buf) {
    const unsigned short* src = buf ? Vlo : Vhi;
    unsigned short* dst = buf ? VTlo : VThi;
    ushort4 v = *(const ushort4*)&src[base + (size_t)(s0 + sl) * DHEAD + d0 + c4];
    __syncthreads();   // protect ls from previous buf's readers
    ls[sl][c4 + 0] = v.x; ls[sl][c4 + 1] = v.y;
    ls[sl][c4 + 2] = v.z; ls[sl][c4 + 3] = v.w;
    __syncthreads();
    ushort4 o;
    o.x = ls[c4 + 0][sl]; o.y = ls[c4 + 1][sl];
    o.z = ls[c4 + 2][sl]; o.w = ls[c4 + 3][sl];
    *(ushort4*)&dst[base + (size_t)(d0 + sl) * S + s0 + c4] = o;
  }
}

// ---------------------------------------------------------------------------
// Embedding dense(64->1024) + relu + timing signal + LayerNorm.
__global__ __launch_bounds__(256) void embed_ln_kernel(
    const float* __restrict__ x, const float* __restrict__ Wemb,
    const float* __restrict__ bemb, const float* __restrict__ g0,
    const float* __restrict__ beta0, float* __restrict__ h0,
    unsigned short* __restrict__ h0hi, unsigned short* __restrict__ h0lo, int S)
{
  __shared__ __align__(16) float xs[FIN];
  __shared__ float red[8];
  int row = blockIdx.x;
  int s   = row % S;
  int tid = threadIdx.x;
  if (tid < FIN / 4)
    *(float4*)&xs[tid * 4] = *(const float4*)&x[(size_t)row * FIN + tid * 4];
  __syncthreads();

  float acc[4];
#pragma unroll
  for (int j = 0; j < 4; ++j) acc[j] = bemb[tid + 256 * j];
#pragma unroll 8
  for (int f = 0; f < FIN; ++f) {
    float xf = xs[f];
    const float* wrow = Wemb + (size_t)f * D_MODEL + tid;
#pragma unroll
    for (int j = 0; j < 4; ++j) acc[j] = fmaf(xf, wrow[256 * j], acc[j]);
  }

  const float log_inc = 0.0180241487920284f;  // ln(10000)/511
  float ps = (float)s;
  float val[4];
#pragma unroll
  for (int j = 0; j < 4; ++j) {
    int d = tid + 256 * j;
    float ts;
    if (d < 512) ts = sinf(ps * expf(-(float)d * log_inc));
    else         ts = cosf(ps * expf(-(float)(d - 512) * log_inc));
    val[j] = fmaxf(acc[j], 0.f) + ts;
  }

  float sum = 0.f, ss = 0.f;
#pragma unroll
  for (int j = 0; j < 4; ++j) { sum += val[j]; ss += val[j] * val[j]; }
  block_reduce2(sum, ss, red);
  float mu  = sum * (1.f / D_MODEL);
  float var = ss * (1.f / D_MODEL) - mu * mu;
  float inv = rsqrtf(var + LN_EPS);
#pragma unroll
  for (int j = 0; j < 4; ++j) {
    int d = tid + 256 * j;
    float v = (val[j] - mu) * inv * g0[d] + beta0[d];
    size_t idx = (size_t)row * D_MODEL + d;
    h0[idx] = v;
    unsigned short h, l;
    bfsplit(v, h, l);
    h0hi[idx] = h; h0lo[idx] = l;
  }
}

// ---------------------------------------------------------------------------
// Split-bf16 MFMA GEMM.  C[M,N] = act((A[M,K] @ B^T[N,K] + bias) * oscale)
// out modes: split=0 -> fp32 C; split=1 -> bf16 hi/lo. headmode=1 additionally
// permutes [b*S+s][h*DH+dh] -> [(b*H+h)*S+s][dh]  (S=2048, H=16, DH=128).
__global__ __launch_bounds__(256) void gemm_bf16s_kernel(
    const unsigned short* __restrict__ Ahi, const unsigned short* __restrict__ Alo,
    const unsigned short* __restrict__ Bhi, const unsigned short* __restrict__ Blo,
    const float* __restrict__ bias, float* __restrict__ C,
    unsigned short* __restrict__ Chi, unsigned short* __restrict__ Clo,
    int M, int N, int K, int relu, int split, int headmode, float oscale)
{
  __shared__ unsigned short lds[4][128][32];   // Ahi, Alo, Bhi, Blo
  int tid = threadIdx.x;
  int w = tid >> 6, lane = tid & 63;
  int m0 = blockIdx.y * 128, n0 = blockIdx.x * 128;
  int wm = (w >> 1) * 64, wn = (w & 1) * 64;
  int fl = lane & 15, fh = lane >> 4;

  f32x4 acc[4][4];
#pragma unroll
  for (int i = 0; i < 4; ++i)
#pragma unroll
    for (int j = 0; j < 4; ++j)
#pragma unroll
      for (int r = 0; r < 4; ++r) acc[i][j][r] = 0.f;

  const unsigned short* gbase[4];
  gbase[0] = Ahi + (size_t)m0 * K;
  gbase[1] = Alo + (size_t)m0 * K;
  gbase[2] = Bhi + (size_t)n0 * K;
  gbase[3] = Blo + (size_t)n0 * K;
  int srow = w * 16 + (lane >> 2);
  int scol = (lane & 3) * 8;

  for (int kt = 0; kt < K; kt += 32) {
    __syncthreads();
#pragma unroll
    for (int t = 0; t < 4; ++t) {
#pragma unroll
      for (int r = 0; r < 2; ++r) {
        const unsigned short* src = gbase[t] + (size_t)(r * 64 + srow) * K + kt + scol;
        GLOAD_LDS(src, &lds[t][r * 64 + w * 16][0]);
      }
    }
    __syncthreads();

    short8 ah[4], al[4];
#pragma unroll
    for (int i = 0; i < 4; ++i) {
      ah[i] = *(const short8*)&lds[0][wm + i * 16 + fl][fh * 8];
      al[i] = *(const short8*)&lds[1][wm + i * 16 + fl][fh * 8];
    }
#pragma unroll
    for (int j = 0; j < 4; ++j) {
      short8 bh = *(const short8*)&lds[2][wn + j * 16 + fl][fh * 8];
      short8 bl = *(const short8*)&lds[3][wn + j * 16 + fl][fh * 8];
#pragma unroll
      for (int i = 0; i < 4; ++i) {
        acc[i][j] = __builtin_amdgcn_mfma_f32_16x16x32_bf16(ah[i], bh, acc[i][j], 0, 0, 0);
        acc[i][j] = __builtin_amdgcn_mfma_f32_16x16x32_bf16(ah[i], bl, acc[i][j], 0, 0, 0);
        acc[i][j] = __builtin_amdgcn_mfma_f32_16x16x32_bf16(al[i], bh, acc[i][j], 0, 0, 0);
      }
    }
  }

#pragma unroll
  for (int j = 0; j < 4; ++j) {
    int gc = n0 + wn + j * 16 + fl;
    float bv = bias[gc];
#pragma unroll
    for (int i = 0; i < 4; ++i) {
      int gr = m0 + wm + i * 16 + fh * 4;
#pragma unroll
      for (int r = 0; r < 4; ++r) {
        float v = (acc[i][j][r] + bv) * oscale;
        if (relu) v = fmaxf(v, 0.f);
        if (split) {
          unsigned short h, l;
          bfsplit(v, h, l);
          size_t o;
          if (headmode) {
            int row = gr + r;   // b*2048 + s
            o = (((size_t)(row >> 11) * NHEADS + (gc >> 7)) * 2048 + (row & 2047)) * DHEAD + (gc & 127);
          } else {
            o = (size_t)(gr + r) * N + gc;
          }
          Chi[o] = h; Clo[o] = l;
        } else {
          C[(size_t)(gr + r) * N + gc] = v;
        }
      }
    }
  }
}

// ---------------------------------------------------------------------------
// MFMA causal flash attention. grid=(S/64, B*H), heavy q-tiles first.
// 4 waves; wave w owns q rows [qb+16w, qb+16w+16). Q pre-scaled by log2e/√S
// (folded into Q-GEMM). Split-bf16 QK^T and PV; softmax in exp2 domain;
// P round-trips per-wave LDS (no barrier needed; DS ops are in-order per
// wave). Layouts match the verified GEMM frag convention:
// C row=(lane>>4)*4+r, col=lane&15.
__global__ __launch_bounds__(256) void attn_mfma_kernel(
    const unsigned short* __restrict__ Qhi, const unsigned short* __restrict__ Qlo,
    const unsigned short* __restrict__ Khi, const unsigned short* __restrict__ Klo,
    const unsigned short* __restrict__ VThi, const unsigned short* __restrict__ VTlo,
    unsigned short* __restrict__ Ohi, unsigned short* __restrict__ Olo, int S)
{
  __shared__ unsigned short Kh[32][136], Kl[32][136];   // [k][dh], +8 pad
  __shared__ unsigned short Vh[128][40], Vl[128][40];   // [dh][k], +8 pad
  __shared__ unsigned short Ph[4][16][40], Pl[4][16][40]; // per-wave P

  int bh = blockIdx.y;
  int qb = ((int)gridDim.x - 1 - (int)blockIdx.x) * 64;   // heavy first
  int tid = threadIdx.x, w = tid >> 6, lane = tid & 63;
  int fl = lane & 15, fh = lane >> 4;
  size_t hb = (size_t)bh * S * DHEAD;

  // Q A-frags: row=fl, k-chunk=fh*8, 4 dh-chunks, hi/lo
  short8 qh[4], ql[4];
  {
    size_t qoff = hb + (size_t)(qb + w * 16 + fl) * DHEAD + fh * 8;
#pragma unroll
    for (int c = 0; c < 4; ++c) {
      qh[c] = *(const short8*)&Qhi[qoff + c * 32];
      ql[c] = *(const short8*)&Qlo[qoff + c * 32];
    }
  }

  f32x4 acc[8];
#pragma unroll
  for (int t = 0; t < 8; ++t)
#pragma unroll
    for (int r = 0; r < 4; ++r) acc[t][r] = 0.f;
  float m[4] = {-1e38f, -1e38f, -1e38f, -1e38f};
  float l[4] = {0.f, 0.f, 0.f, 0.f};

  const int qmin = qb + w * 16;
  const int qmax = qmin + 15;
  const int nkt = (qb + 64) >> 5;

  for (int kt = 0; kt < nkt; ++kt) {
    const int k0 = kt << 5;
    __syncthreads();   // previous tile consumed
#pragma unroll
    for (int p = 0; p < 2; ++p) {
      int kr = (tid >> 4) + p * 16, kc = (tid & 15) * 8;
      size_t g = hb + (size_t)(k0 + kr) * DHEAD + kc;
      *(short8*)&Kh[kr][kc] = *(const short8*)&Khi[g];
      *(short8*)&Kl[kr][kc] = *(const short8*)&Klo[g];
      int vr = (tid >> 2) + p * 64, vc = (tid & 3) * 8;
      size_t gv = hb + (size_t)vr * S + k0 + vc;
      *(short8*)&Vh[vr][vc] = *(const short8*)&VThi[gv];
      *(short8*)&Vl[vr][vc] = *(const short8*)&VTlo[gv];
    }
    __syncthreads();
    if (k0 > qmax) continue;   // fully masked for this wave

    // QK^T: 2 k-subtiles x 4 dh-chunks x 3 mfma
    f32x4 s0 = {0.f, 0.f, 0.f, 0.f}, s1 = {0.f, 0.f, 0.f, 0.f};
#pragma unroll
    for (int c = 0; c < 4; ++c) {
      short8 k0h = *(const short8*)&Kh[fl][c * 32 + fh * 8];
      short8 k0l = *(const short8*)&Kl[fl][c * 32 + fh * 8];
      short8 k1h = *(const short8*)&Kh[16 + fl][c * 32 + fh * 8];
      short8 k1l = *(const short8*)&Kl[16 + fl][c * 32 + fh * 8];
      s0 = __builtin_amdgcn_mfma_f32_16x16x32_bf16(qh[c], k0h, s0, 0, 0, 0);
      s0 = __builtin_amdgcn_mfma_f32_16x16x32_bf16(qh[c], k0l, s0, 0, 0, 0);
      s0 = __builtin_amdgcn_mfma_f32_16x16x32_bf16(ql[c], k0h, s0, 0, 0, 0);
      s1 = __builtin_amdgcn_mfma_f32_16x16x32_bf16(qh[c], k1h, s1, 0, 0, 0);
      s1 = __builtin_amdgcn_mfma_f32_16x16x32_bf16(qh[c], k1l, s1, 0, 0, 0);
      s1 = __builtin_amdgcn_mfma_f32_16x16x32_bf16(ql[c], k1h, s1, 0, 0, 0);
    }
    if (k0 + 31 > qmin) {     // edge tile: apply causal mask
#pragma unroll
      for (int r = 0; r < 4; ++r) {
        int q = qmin + fh * 4 + r;
        if (k0 + fl > q)      s0[r] = -1e38f;
        if (k0 + 16 + fl > q) s1[r] = -1e38f;
      }
    }

    float so[4];
#pragma unroll
    for (int r = 0; r < 4; ++r) {
      float tm = fmaxf(s0[r], s1[r]);
      tm = fmaxf(tm, __shfl_xor(tm, 1));
      tm = fmaxf(tm, __shfl_xor(tm, 2));
      tm = fmaxf(tm, __shfl_xor(tm, 4));
      tm = fmaxf(tm, __shfl_xor(tm, 8));
      float mn = fmaxf(m[r], tm);
      so[r] = exp2f(m[r] - mn);
      m[r] = mn;
      float p0 = exp2f(s0[r] - mn);
      float p1 = exp2f(s1[r] - mn);
      unsigned short hh, ll;
      bfsplit(p0, hh, ll);
      Ph[w][fh * 4 + r][fl] = hh;      Pl[w][fh * 4 + r][fl] = ll;
      bfsplit(p1, hh, ll);
      Ph[w][fh * 4 + r][16 + fl] = hh; Pl[w][fh * 4 + r][16 + fl] = ll;
      float rs = p0 + p1;
      rs += __shfl_xor(rs, 1);
      rs += __shfl_xor(rs, 2);
      rs += __shfl_xor(rs, 4);
      rs += __shfl_xor(rs, 8);
      l[r] = l[r] * so[r] + rs;
    }
#pragma unroll
    for (int t = 0; t < 8; ++t)
#pragma unroll
      for (int r = 0; r < 4; ++r) acc[t][r] *= so[r];

    // PV: A = P (same-wave LDS round-trip), B = V^T frags
    short8 pah = *(const short8*)&Ph[w][fl][fh * 8];
    short8 pal = *(const short8*)&Pl[w][fl][fh * 8];
#pragma unroll
    for (int t = 0; t < 8; ++t) {
      short8 vth = *(const short8*)&Vh[t * 16 + fl][fh * 8];
      short8 vtl = *(const short8*)&Vl[t * 16 + fl][fh * 8];
      acc[t] = __builtin_amdgcn_mfma_f32_16x16x32_bf16(pah, vth, acc[t], 0, 0, 0);
      acc[t] = __builtin_amdgcn_mfma_f32_16x16x32_bf16(pah, vtl, acc[t], 0, 0, 0);
      acc[t] = __builtin_amdgcn_mfma_f32_16x16x32_bf16(pal, vth, acc[t], 0, 0, 0);
    }
  }

  int b_ = bh >> 4, h_ = bh & 15;
  float inv[4];
#pragma unroll
  for (int r = 0; r < 4; ++r) inv[r] = 1.f / l[r];
#pragma unroll
  for (int t = 0; t < 8; ++t) {
#pragma unroll
    for (int r = 0; r < 4; ++r) {
      float v = acc[t][r] * inv[r];
      size_t o = ((size_t)b_ * S + qb + w * 16 + fh * 4 + r) * ATTF + h_ * DHEAD + t * 16 + fl;
      unsigned short hh, ll;
      bfsplit(v, hh, ll);
      Ohi[o] = hh; Olo[o] = ll;
    }
  }
}

// ---------------------------------------------------------------------------
// out = LN(a + r); optionally also bf16 hi/lo split of out.
__global__ __launch_bounds__(256) void resid_ln_kernel(
    const float* __restrict__ a, const float* __restrict__ r,
    const float* __restrict__ gamma, const float* __restrict__ beta,
    float* __restrict__ out, unsigned short* __restrict__ ohi,
    unsigned short* __restrict__ olo)
{
  __shared__ float red[8];
  size_t row = blockIdx.x;
  int tid = threadIdx.x;
  float4 av = *(const float4*)&a[row * D_MODEL + tid * 4];
  float4 rv = *(const float4*)&r[row * D_MODEL + tid * 4];
  float val[4] = {av.x + rv.x, av.y + rv.y, av.z + rv.z, av.w + rv.w};
  float sum = val[0] + val[1] + val[2] + val[3];
  float ss  = val[0] * val[0] + val[1] * val[1] + val[2] * val[2] + val[3] * val[3];
  block_reduce2(sum, ss, red);
  float mu  = sum * (1.f / D_MODEL);
  float var = ss * (1.f / D_MODEL) - mu * mu;
  float inv = rsqrtf(var + LN_EPS);
  float4 gv = *(const float4*)&gamma[tid * 4];
  float4 bv = *(const float4*)&beta[tid * 4];
  float o[4];
  o[0] = (val[0] - mu) * inv * gv.x + bv.x;
  o[1] = (val[1] - mu) * inv * gv.y + bv.y;
  o[2] = (val[2] - mu) * inv * gv.z + bv.z;
  o[3] = (val[3] - mu) * inv * gv.w + bv.w;
  *(float4*)&out[row * D_MODEL + tid * 4] = *(float4*)o;
  if (ohi) {
    ushort4 h4, l4;
    unsigned short h, l;
    bfsplit(o[0], h, l); h4.x = h; l4.x = l;
    bfsplit(o[1], h, l); h4.y = h; l4.y = l;
    bfsplit(o[2], h, l); h4.z = h; l4.z = l;
    bfsplit(o[3], h, l); h4.w = h; l4.w = l;
    *(ushort4*)&ohi[row * D_MODEL + tid * 4] = h4;
    *(ushort4*)&olo[row * D_MODEL + tid * 4] = l4;
  }
}

// ---------------------------------------------------------------------------
extern "C" void kernel_launch(void* const* d_in, const int* in_sizes, int n_in,
                              void* d_out, int out_size, void* d_ws, size_t ws_size,
                              hipStream_t stream) {
  const float* x     = (const float*)d_in[0];
  const float* W_emb = (const float*)d_in[1];
  const float* b_emb = (const float*)d_in[2];
  const float* g0    = (const float*)d_in[3];
  const float* beta0 = (const float*)d_in[4];
  const float* Wq    = (const float*)d_in[5];
  const float* bq    = (const float*)d_in[6];
  const float* Wk    = (const float*)d_in[7];
  const float* bk    = (const float*)d_in[8];
  const float* Wv    = (const float*)d_in[9];
  const float* bv    = (const float*)d_in[10];
  const float* Wo    = (const float*)d_in[11];
  const float* bo    = (const float*)d_in[12];
  const float* g1    = (const float*)d_in[13];
  const float* beta1 = (const float*)d_in[14];
  const float* W1    = (const float*)d_in[15];
  const float* b1    = (const float*)d_in[16];
  const float* W2    = (const float*)d_in[17];
  const float* b2    = (const float*)d_in[18];
  const float* g2    = (const float*)d_in[19];
  const float* beta2 = (const float*)d_in[20];
  float* out = (float*)d_out;
  char* W = (char*)d_ws;

  const int S  = 2048;
  const int BS = in_sizes[0] / FIN;       // 4096
  const int B  = BS / S;                  // 2
  const size_t MB = 1024 * 1024;
  const float qscale = 1.4426950408889634f / sqrtf((float)S);  // log2e/sqrt(S)

  // workspace layout (byte offsets; 224 MB total, aliases per liveness)
  unsigned short* wqThi = (unsigned short*)(W + 0 * MB);
  unsigned short* wqTlo = (unsigned short*)(W + 4 * MB);
  unsigned short* wkThi = (unsigned short*)(W + 8 * MB);
  unsigned short* wkTlo = (unsigned short*)(W + 12 * MB);
  unsigned short* wvThi = (unsigned short*)(W + 16 * MB);
  unsigned short* wvTlo = (unsigned short*)(W + 20 * MB);
  unsigned short* woThi = (unsigned short*)(W + 24 * MB);
  unsigned short* woTlo = (unsigned short*)(W + 28 * MB);
  unsigned short* w1Thi = (unsigned short*)(W + 32 * MB);
  unsigned short* w1Tlo = (unsigned short*)(W + 40 * MB);
  unsigned short* w2Thi = (unsigned short*)(W + 48 * MB);
  unsigned short* w2Tlo = (unsigned short*)(W + 56 * MB);
  float*          h0f   = (float*)        (W + 64 * MB);
  unsigned short* h0hi  = (unsigned short*)(W + 80 * MB);
  unsigned short* h0lo  = (unsigned short*)(W + 88 * MB);
  unsigned short* Qhi_  = (unsigned short*)(W + 96 * MB);   // [(bh)][s][dh]
  unsigned short* Qlo_  = (unsigned short*)(W + 112 * MB);
  unsigned short* Khi_  = (unsigned short*)(W + 128 * MB);
  unsigned short* Klo_  = (unsigned short*)(W + 144 * MB);
  unsigned short* Vhi_  = (unsigned short*)(W + 160 * MB);
  unsigned short* Vlo_  = (unsigned short*)(W + 176 * MB);
  unsigned short* VThi_ = (unsigned short*)(W + 192 * MB);  // [(bh)][dh][s]
  unsigned short* VTlo_ = (unsigned short*)(W + 208 * MB);
  unsigned short* ctxhi = (unsigned short*)(W + 160 * MB);  // over V (dead)
  unsigned short* ctxlo = (unsigned short*)(W + 176 * MB);
  float*          ao    = (float*)        (W + 96 * MB);    // over Q (dead)
  float*          h1f   = (float*)        (W + 112 * MB);   // over Qlo (dead)
  unsigned short* h1hi  = (unsigned short*)(W + 128 * MB);  // over Khi (dead)
  unsigned short* h1lo  = (unsigned short*)(W + 136 * MB);
  unsigned short* midhi = (unsigned short*)(W + 144 * MB);  // over Klo+ctxhi (dead)
  unsigned short* midlo = (unsigned short*)(W + 176 * MB);  // over ctxlo+VThi (dead)
  float*          f2    = (float*)        (W + 208 * MB);   // over VTlo (dead)

  // 0) weight transpose + split
  transpose_split_kernel<<<dim3(ATTF / 32, D_MODEL / 32), 256, 0, stream>>>(Wq, wqThi, wqTlo, D_MODEL, ATTF);
  transpose_split_kernel<<<dim3(ATTF / 32, D_MODEL / 32), 256, 0, stream>>>(Wk, wkThi, wkTlo, D_MODEL, ATTF);
  transpose_split_kernel<<<dim3(ATTF / 32, D_MODEL / 32), 256, 0, stream>>>(Wv, wvThi, wvTlo, D_MODEL, ATTF);
  transpose_split_kernel<<<dim3(D_MODEL / 32, ATTF / 32), 256, 0, stream>>>(Wo, woThi, woTlo, ATTF, D_MODEL);
  transpose_split_kernel<<<dim3(4 * D_MODEL / 32, D_MODEL / 32), 256, 0, stream>>>(W1, w1Thi, w1Tlo, D_MODEL, 4 * D_MODEL);
  transpose_split_kernel<<<dim3(D_MODEL / 32, 4 * D_MODEL / 32), 256, 0, stream>>>(W2, w2Thi, w2Tlo, 4 * D_MODEL, D_MODEL);

  // 1) embed + timing + LN0
  embed_ln_kernel<<<BS, 256, 0, stream>>>(x, W_emb, b_emb, g0, beta0, h0f, h0hi, h0lo, S);

  // 2) q,k,v projections -> head-major bf16 hi/lo (Q pre-scaled, exp2 domain)
  gemm_bf16s_kernel<<<dim3(ATTF / 128, BS / 128), 256, 0, stream>>>(
      h0hi, h0lo, wqThi, wqTlo, bq, nullptr, Qhi_, Qlo_, BS, ATTF, D_MODEL, 0, 1, 1, qscale);
  gemm_bf16s_kernel<<<dim3(ATTF / 128, BS / 128), 256, 0, stream>>>(
      h0hi, h0lo, wkThi, wkTlo, bk, nullptr, Khi_, Klo_, BS, ATTF, D_MODEL, 0, 1, 1, 1.f);
  gemm_bf16s_kernel<<<dim3(ATTF / 128, BS / 128), 256, 0, stream>>>(
      h0hi, h0lo, wvThi, wvTlo, bv, nullptr, Vhi_, Vlo_, BS, ATTF, D_MODEL, 0, 1, 1, 1.f);

  // 3) V transpose per (b,h)
  transpose_v_kernel<<<dim3(S / 32, DHEAD / 32, B * NHEADS), 256, 0, stream>>>(
      Vhi_, Vlo_, VThi_, VTlo_, S);

  // 4) MFMA causal attention -> ctx hi/lo [bs][2048]
  attn_mfma_kernel<<<dim3(S / 64, B * NHEADS), 256, 0, stream>>>(
      Qhi_, Qlo_, Khi_, Klo_, VThi_, VTlo_, ctxhi, ctxlo, S);

  // 5) output projection -> ao fp32
  gemm_bf16s_kernel<<<dim3(D_MODEL / 128, BS / 128), 256, 0, stream>>>(
      ctxhi, ctxlo, woThi, woTlo, bo, ao, nullptr, nullptr, BS, D_MODEL, ATTF, 0, 0, 0, 1.f);

  // 6) h1 = LN(h0 + ao), + hi/lo split
  resid_ln_kernel<<<BS, 256, 0, stream>>>(h0f, ao, g1, beta1, h1f, h1hi, h1lo);

  // 7) FFN up (relu) -> mid hi/lo
  gemm_bf16s_kernel<<<dim3(4 * D_MODEL / 128, BS / 128), 256, 0, stream>>>(
      h1hi, h1lo, w1Thi, w1Tlo, b1, nullptr, midhi, midlo, BS, 4 * D_MODEL, D_MODEL, 1, 1, 0, 1.f);

  // 8) FFN down -> f2 fp32
  gemm_bf16s_kernel<<<dim3(D_MODEL / 128, BS / 128), 256, 0, stream>>>(
      midhi, midlo, w2Thi, w2Tlo, b2, f2, nullptr, nullptr, BS, D_MODEL, 4 * D_MODEL, 0, 0, 0, 1.f);

  // 9) out = LN(h1 + f2)
  resid_ln_kernel<<<BS, 256, 0, stream>>>(h1f, f2, g2, beta2, out, nullptr, nullptr);
}

// Round 8
// 1227.831 us; speedup vs baseline: 3.6571x; 1.1299x over previous
//
#include <hip/hip_runtime.h>
#include <hip/hip_bf16.h>
#include <math.h>

// FFNN_encoder, round 8.
// R8: attention geometry — 512-thread (8-wave) blocks, QBLK=128 (each wave
// keeps its 16-row flash pipeline; K/V staged once per 128 q-rows instead of
// 64). LDS 58.4KB -> 2 blocks/CU = 16 waves/CU (was 12). s_setprio around
// MFMA clusters. Everything else unchanged from the measured R7 kernel.

#define D_MODEL 1024
#define NHEADS  16
#define DHEAD   128
#define ATTF    2048
#define FIN     64
#define LN_EPS  1e-3f

typedef __attribute__((ext_vector_type(8))) short short8;
typedef __attribute__((ext_vector_type(4))) float f32x4;

#define GLOAD_LDS(gp, lp) \
  __builtin_amdgcn_global_load_lds((const __attribute__((address_space(1))) void*)(gp), \
                                   (__attribute__((address_space(3))) void*)(lp), 16, 0, 0)

// bf16 RNE conversion (bit-level, finite values only)
__device__ __forceinline__ unsigned short f2bf(float f) {
  unsigned int x = __float_as_uint(f);
  return (unsigned short)((x + 0x7fffu + ((x >> 16) & 1u)) >> 16);
}
__device__ __forceinline__ float bf2f(unsigned short u) {
  return __uint_as_float(((unsigned int)u) << 16);
}
__device__ __forceinline__ void bfsplit(float f, unsigned short& hi, unsigned short& lo) {
  hi = f2bf(f);
  lo = f2bf(f - bf2f(hi));
}

// ---------------------------------------------------------------------------
__device__ __forceinline__ void block_reduce2(float& a, float& b, float* sbuf) {
#pragma unroll
  for (int off = 32; off > 0; off >>= 1) {
    a += __shfl_xor(a, off);
    b += __shfl_xor(b, off);
  }
  int lane = threadIdx.x & 63;
  int w    = threadIdx.x >> 6;
  if (lane == 0) { sbuf[w] = a; sbuf[4 + w] = b; }
  __syncthreads();
  a = sbuf[0] + sbuf[1] + sbuf[2] + sbuf[3];
  b = sbuf[4] + sbuf[5] + sbuf[6] + sbuf[7];
}

// ---------------------------------------------------------------------------
// Weight transpose + bf16 hi/lo split.  W[K][N] fp32 -> T[N][K] bf16 x2
__global__ __launch_bounds__(256) void transpose_split_kernel(
    const float* __restrict__ W, unsigned short* __restrict__ Thi,
    unsigned short* __restrict__ Tlo, int K, int N)
{
  __shared__ float ls[32][33];
  int n0 = blockIdx.x * 32, k0 = blockIdx.y * 32;
  int t = threadIdx.x;
  int kl = t >> 3, nl4 = (t & 7) * 4;
  float4 v = *(const float4*)&W[(size_t)(k0 + kl) * N + n0 + nl4];
  ls[kl][nl4 + 0] = v.x; ls[kl][nl4 + 1] = v.y;
  ls[kl][nl4 + 2] = v.z; ls[kl][nl4 + 3] = v.w;
  __syncthreads();
  int nl = t >> 3, kl4 = (t & 7) * 4;
  ushort4 h4, l4;
  unsigned short h, l;
  bfsplit(ls[kl4 + 0][nl], h, l); h4.x = h; l4.x = l;
  bfsplit(ls[kl4 + 1][nl], h, l); h4.y = h; l4.y = l;
  bfsplit(ls[kl4 + 2][nl], h, l); h4.z = h; l4.z = l;
  bfsplit(ls[kl4 + 3][nl], h, l); h4.w = h; l4.w = l;
  size_t o = (size_t)(n0 + nl) * K + k0 + kl4;
  *(ushort4*)&Thi[o] = h4;
  *(ushort4*)&Tlo[o] = l4;
}

// ---------------------------------------------------------------------------
// V transpose per (b,h): V[(bh)][s][dh] -> VT[(bh)][dh][s], bf16 hi/lo
__global__ __launch_bounds__(256) void transpose_v_kernel(
    const unsigned short* __restrict__ Vhi, const unsigned short* __restrict__ Vlo,
    unsigned short* __restrict__ VThi, unsigned short* __restrict__ VTlo, int S)
{
  __shared__ unsigned short ls[32][36];
  int s0 = blockIdx.x * 32, d0 = blockIdx.y * 32;
  int bh = blockIdx.z;
  size_t base = (size_t)bh * S * DHEAD;
  int t = threadIdx.x;
  int sl = t >> 3, c4 = (t & 7) * 4;
#pragma unroll
  for (int buf = 0; buf < 2; ++buf) {
    const unsigned short* src = buf ? Vlo : Vhi;
    unsigned short* dst = buf ? VTlo : VThi;
    ushort4 v = *(const ushort4*)&src[base + (size_t)(s0 + sl) * DHEAD + d0 + c4];
    __syncthreads();   // protect ls from previous buf's readers
    ls[sl][c4 + 0] = v.x; ls[sl][c4 + 1] = v.y;
    ls[sl][c4 + 2] = v.z; ls[sl][c4 + 3] = v.w;
    __syncthreads();
    ushort4 o;
    o.x = ls[c4 + 0][sl]; o.y = ls[c4 + 1][sl];
    o.z = ls[c4 + 2][sl]; o.w = ls[c4 + 3][sl];
    *(ushort4*)&dst[base + (size_t)(d0 + sl) * S + s0 + c4] = o;
  }
}

// ---------------------------------------------------------------------------
// Embedding dense(64->1024) + relu + timing signal + LayerNorm.
__global__ __launch_bounds__(256) void embed_ln_kernel(
    const float* __restrict__ x, const float* __restrict__ Wemb,
    const float* __restrict__ bemb, const float* __restrict__ g0,
    const float* __restrict__ beta0, float* __restrict__ h0,
    unsigned short* __restrict__ h0hi, unsigned short* __restrict__ h0lo, int S)
{
  __shared__ __align__(16) float xs[FIN];
  __shared__ float red[8];
  int row = blockIdx.x;
  int s   = row % S;
  int tid = threadIdx.x;
  if (tid < FIN / 4)
    *(float4*)&xs[tid * 4] = *(const float4*)&x[(size_t)row * FIN + tid * 4];
  __syncthreads();

  float acc[4];
#pragma unroll
  for (int j = 0; j < 4; ++j) acc[j] = bemb[tid + 256 * j];
#pragma unroll 8
  for (int f = 0; f < FIN; ++f) {
    float xf = xs[f];
    const float* wrow = Wemb + (size_t)f * D_MODEL + tid;
#pragma unroll
    for (int j = 0; j < 4; ++j) acc[j] = fmaf(xf, wrow[256 * j], acc[j]);
  }

  const float log_inc = 0.0180241487920284f;  // ln(10000)/511
  float ps = (float)s;
  float val[4];
#pragma unroll
  for (int j = 0; j < 4; ++j) {
    int d = tid + 256 * j;
    float ts;
    if (d < 512) ts = sinf(ps * expf(-(float)d * log_inc));
    else         ts = cosf(ps * expf(-(float)(d - 512) * log_inc));
    val[j] = fmaxf(acc[j], 0.f) + ts;
  }

  float sum = 0.f, ss = 0.f;
#pragma unroll
  for (int j = 0; j < 4; ++j) { sum += val[j]; ss += val[j] * val[j]; }
  block_reduce2(sum, ss, red);
  float mu  = sum * (1.f / D_MODEL);
  float var = ss * (1.f / D_MODEL) - mu * mu;
  float inv = rsqrtf(var + LN_EPS);
#pragma unroll
  for (int j = 0; j < 4; ++j) {
    int d = tid + 256 * j;
    float v = (val[j] - mu) * inv * g0[d] + beta0[d];
    size_t idx = (size_t)row * D_MODEL + d;
    h0[idx] = v;
    unsigned short h, l;
    bfsplit(v, h, l);
    h0hi[idx] = h; h0lo[idx] = l;
  }
}

// ---------------------------------------------------------------------------
// Split-bf16 MFMA GEMM.  C[M,N] = act((A[M,K] @ B^T[N,K] + bias) * oscale)
// out modes: split=0 -> fp32 C; split=1 -> bf16 hi/lo. headmode=1 additionally
// permutes [b*S+s][h*DH+dh] -> [(b*H+h)*S+s][dh]  (S=2048, H=16, DH=128).
__global__ __launch_bounds__(256) void gemm_bf16s_kernel(
    const unsigned short* __restrict__ Ahi, const unsigned short* __restrict__ Alo,
    const unsigned short* __restrict__ Bhi, const unsigned short* __restrict__ Blo,
    const float* __restrict__ bias, float* __restrict__ C,
    unsigned short* __restrict__ Chi, unsigned short* __restrict__ Clo,
    int M, int N, int K, int relu, int split, int headmode, float oscale)
{
  __shared__ unsigned short lds[4][128][32];   // Ahi, Alo, Bhi, Blo
  int tid = threadIdx.x;
  int w = tid >> 6, lane = tid & 63;
  int m0 = blockIdx.y * 128, n0 = blockIdx.x * 128;
  int wm = (w >> 1) * 64, wn = (w & 1) * 64;
  int fl = lane & 15, fh = lane >> 4;

  f32x4 acc[4][4];
#pragma unroll
  for (int i = 0; i < 4; ++i)
#pragma unroll
    for (int j = 0; j < 4; ++j)
#pragma unroll
      for (int r = 0; r < 4; ++r) acc[i][j][r] = 0.f;

  const unsigned short* gbase[4];
  gbase[0] = Ahi + (size_t)m0 * K;
  gbase[1] = Alo + (size_t)m0 * K;
  gbase[2] = Bhi + (size_t)n0 * K;
  gbase[3] = Blo + (size_t)n0 * K;
  int srow = w * 16 + (lane >> 2);
  int scol = (lane & 3) * 8;

  for (int kt = 0; kt < K; kt += 32) {
    __syncthreads();
#pragma unroll
    for (int t = 0; t < 4; ++t) {
#pragma unroll
      for (int r = 0; r < 2; ++r) {
        const unsigned short* src = gbase[t] + (size_t)(r * 64 + srow) * K + kt + scol;
        GLOAD_LDS(src, &lds[t][r * 64 + w * 16][0]);
      }
    }
    __syncthreads();

    short8 ah[4], al[4];
#pragma unroll
    for (int i = 0; i < 4; ++i) {
      ah[i] = *(const short8*)&lds[0][wm + i * 16 + fl][fh * 8];
      al[i] = *(const short8*)&lds[1][wm + i * 16 + fl][fh * 8];
    }
#pragma unroll
    for (int j = 0; j < 4; ++j) {
      short8 bh = *(const short8*)&lds[2][wn + j * 16 + fl][fh * 8];
      short8 bl = *(const short8*)&lds[3][wn + j * 16 + fl][fh * 8];
#pragma unroll
      for (int i = 0; i < 4; ++i) {
        acc[i][j] = __builtin_amdgcn_mfma_f32_16x16x32_bf16(ah[i], bh, acc[i][j], 0, 0, 0);
        acc[i][j] = __builtin_amdgcn_mfma_f32_16x16x32_bf16(ah[i], bl, acc[i][j], 0, 0, 0);
        acc[i][j] = __builtin_amdgcn_mfma_f32_16x16x32_bf16(al[i], bh, acc[i][j], 0, 0, 0);
      }
    }
  }

#pragma unroll
  for (int j = 0; j < 4; ++j) {
    int gc = n0 + wn + j * 16 + fl;
    float bv = bias[gc];
#pragma unroll
    for (int i = 0; i < 4; ++i) {
      int gr = m0 + wm + i * 16 + fh * 4;
#pragma unroll
      for (int r = 0; r < 4; ++r) {
        float v = (acc[i][j][r] + bv) * oscale;
        if (relu) v = fmaxf(v, 0.f);
        if (split) {
          unsigned short h, l;
          bfsplit(v, h, l);
          size_t o;
          if (headmode) {
            int row = gr + r;   // b*2048 + s
            o = (((size_t)(row >> 11) * NHEADS + (gc >> 7)) * 2048 + (row & 2047)) * DHEAD + (gc & 127);
          } else {
            o = (size_t)(gr + r) * N + gc;
          }
          Chi[o] = h; Clo[o] = l;
        } else {
          C[(size_t)(gr + r) * N + gc] = v;
        }
      }
    }
  }
}

// ---------------------------------------------------------------------------
// MFMA causal flash attention. grid=(S/128, B*H), heavy q-tiles first.
// 512 threads = 8 waves; wave w owns q rows [qb+16w, qb+16w+16), QBLK=128.
// Q pre-scaled by log2e/sqrt(S) (folded into Q-GEMM). Split-bf16 QK^T and PV;
// softmax in exp2 domain; P round-trips per-wave LDS (no barrier needed; DS
// ops are in-order per wave). Frag conventions match the verified GEMM:
// C row=(lane>>4)*4+r, col=lane&15.
__global__ __launch_bounds__(512) void attn_mfma_kernel(
    const unsigned short* __restrict__ Qhi, const unsigned short* __restrict__ Qlo,
    const unsigned short* __restrict__ Khi, const unsigned short* __restrict__ Klo,
    const unsigned short* __restrict__ VThi, const unsigned short* __restrict__ VTlo,
    unsigned short* __restrict__ Ohi, unsigned short* __restrict__ Olo, int S)
{
  __shared__ unsigned short Kh[32][136], Kl[32][136];     // [k][dh], +8 pad
  __shared__ unsigned short Vh[128][40], Vl[128][40];     // [dh][k], +8 pad
  __shared__ unsigned short Ph[8][16][40], Pl[8][16][40]; // per-wave P

  int bh = blockIdx.y;
  int qb = ((int)gridDim.x - 1 - (int)blockIdx.x) * 128;  // heavy first
  int tid = threadIdx.x, w = tid >> 6, lane = tid & 63;
  int fl = lane & 15, fh = lane >> 4;
  size_t hb = (size_t)bh * S * DHEAD;

  // Q A-frags: row=fl, k-chunk=fh*8, 4 dh-chunks, hi/lo
  short8 qh[4], ql[4];
  {
    size_t qoff = hb + (size_t)(qb + w * 16 + fl) * DHEAD + fh * 8;
#pragma unroll
    for (int c = 0; c < 4; ++c) {
      qh[c] = *(const short8*)&Qhi[qoff + c * 32];
      ql[c] = *(const short8*)&Qlo[qoff + c * 32];
    }
  }

  f32x4 acc[8];
#pragma unroll
  for (int t = 0; t < 8; ++t)
#pragma unroll
    for (int r = 0; r < 4; ++r) acc[t][r] = 0.f;
  float m[4] = {-1e38f, -1e38f, -1e38f, -1e38f};
  float l[4] = {0.f, 0.f, 0.f, 0.f};

  const int qmin = qb + w * 16;
  const int qmax = qmin + 15;
  const int nkt = (qb + 128) >> 5;

  // staging indices (512 threads, one pass per buffer)
  const int kr = tid >> 4, kc = (tid & 15) * 8;   // K: 32 rows x 128 cols
  const int vr = tid >> 2, vc = (tid & 3) * 8;    // V: 128 rows x 32 cols

  for (int kt = 0; kt < nkt; ++kt) {
    const int k0 = kt << 5;
    __syncthreads();   // previous tile consumed
    {
      size_t g = hb + (size_t)(k0 + kr) * DHEAD + kc;
      *(short8*)&Kh[kr][kc] = *(const short8*)&Khi[g];
      *(short8*)&Kl[kr][kc] = *(const short8*)&Klo[g];
      size_t gv = hb + (size_t)vr * S + k0 + vc;
      *(short8*)&Vh[vr][vc] = *(const short8*)&VThi[gv];
      *(short8*)&Vl[vr][vc] = *(const short8*)&VTlo[gv];
    }
    __syncthreads();
    if (k0 > qmax) continue;   // fully masked for this wave; barriers above

    // QK^T: 2 k-subtiles x 4 dh-chunks x 3 mfma
    f32x4 s0 = {0.f, 0.f, 0.f, 0.f}, s1 = {0.f, 0.f, 0.f, 0.f};
    __builtin_amdgcn_s_setprio(1);
#pragma unroll
    for (int c = 0; c < 4; ++c) {
      short8 k0h = *(const short8*)&Kh[fl][c * 32 + fh * 8];
      short8 k0l = *(const short8*)&Kl[fl][c * 32 + fh * 8];
      short8 k1h = *(const short8*)&Kh[16 + fl][c * 32 + fh * 8];
      short8 k1l = *(const short8*)&Kl[16 + fl][c * 32 + fh * 8];
      s0 = __builtin_amdgcn_mfma_f32_16x16x32_bf16(qh[c], k0h, s0, 0, 0, 0);
      s0 = __builtin_amdgcn_mfma_f32_16x16x32_bf16(qh[c], k0l, s0, 0, 0, 0);
      s0 = __builtin_amdgcn_mfma_f32_16x16x32_bf16(ql[c], k0h, s0, 0, 0, 0);
      s1 = __builtin_amdgcn_mfma_f32_16x16x32_bf16(qh[c], k1h, s1, 0, 0, 0);
      s1 = __builtin_amdgcn_mfma_f32_16x16x32_bf16(qh[c], k1l, s1, 0, 0, 0);
      s1 = __builtin_amdgcn_mfma_f32_16x16x32_bf16(ql[c], k1h, s1, 0, 0, 0);
    }
    __builtin_amdgcn_s_setprio(0);
    if (k0 + 31 > qmin) {     // edge tile: apply causal mask
#pragma unroll
      for (int r = 0; r < 4; ++r) {
        int q = qmin + fh * 4 + r;
        if (k0 + fl > q)      s0[r] = -1e38f;
        if (k0 + 16 + fl > q) s1[r] = -1e38f;
      }
    }

    float so[4];
#pragma unroll
    for (int r = 0; r < 4; ++r) {
      float tm = fmaxf(s0[r], s1[r]);
      tm = fmaxf(tm, __shfl_xor(tm, 1));
      tm = fmaxf(tm, __shfl_xor(tm, 2));
      tm = fmaxf(tm, __shfl_xor(tm, 4));
      tm = fmaxf(tm, __shfl_xor(tm, 8));
      float mn = fmaxf(m[r], tm);
      so[r] = exp2f(m[r] - mn);
      m[r] = mn;
      float p0 = exp2f(s0[r] - mn);
      float p1 = exp2f(s1[r] - mn);
      unsigned short hh, ll;
      bfsplit(p0, hh, ll);
      Ph[w][fh * 4 + r][fl] = hh;      Pl[w][fh * 4 + r][fl] = ll;
      bfsplit(p1, hh, ll);
      Ph[w][fh * 4 + r][16 + fl] = hh; Pl[w][fh * 4 + r][16 + fl] = ll;
      float rs = p0 + p1;
      rs += __shfl_xor(rs, 1);
      rs += __shfl_xor(rs, 2);
      rs += __shfl_xor(rs, 4);
      rs += __shfl_xor(rs, 8);
      l[r] = l[r] * so[r] + rs;
    }
#pragma unroll
    for (int t = 0; t < 8; ++t)
#pragma unroll
      for (int r = 0; r < 4; ++r) acc[t][r] *= so[r];

    // PV: A = P (same-wave LDS round-trip), B = V^T frags
    short8 pah = *(const short8*)&Ph[w][fl][fh * 8];
    short8 pal = *(const short8*)&Pl[w][fl][fh * 8];
    __builtin_amdgcn_s_setprio(1);
#pragma unroll
    for (int t = 0; t < 8; ++t) {
      short8 vth = *(const short8*)&Vh[t * 16 + fl][fh * 8];
      short8 vtl = *(const short8*)&Vl[t * 16 + fl][fh * 8];
      acc[t] = __builtin_amdgcn_mfma_f32_16x16x32_bf16(pah, vth, acc[t], 0, 0, 0);
      acc[t] = __builtin_amdgcn_mfma_f32_16x16x32_bf16(pah, vtl, acc[t], 0, 0, 0);
      acc[t] = __builtin_amdgcn_mfma_f32_16x16x32_bf16(pal, vth, acc[t], 0, 0, 0);
    }
    __builtin_amdgcn_s_setprio(0);
  }

  int b_ = bh >> 4, h_ = bh & 15;
  float inv[4];
#pragma unroll
  for (int r = 0; r < 4; ++r) inv[r] = 1.f / l[r];
#pragma unroll
  for (int t = 0; t < 8; ++t) {
#pragma unroll
    for (int r = 0; r < 4; ++r) {
      float v = acc[t][r] * inv[r];
      size_t o = ((size_t)b_ * S + qb + w * 16 + fh * 4 + r) * ATTF + h_ * DHEAD + t * 16 + fl;
      unsigned short hh, ll;
      bfsplit(v, hh, ll);
      Ohi[o] = hh; Olo[o] = ll;
    }
  }
}

// ---------------------------------------------------------------------------
// out = LN(a + r); optionally also bf16 hi/lo split of out.
__global__ __launch_bounds__(256) void resid_ln_kernel(
    const float* __restrict__ a, const float* __restrict__ r,
    const float* __restrict__ gamma, const float* __restrict__ beta,
    float* __restrict__ out, unsigned short* __restrict__ ohi,
    unsigned short* __restrict__ olo)
{
  __shared__ float red[8];
  size_t row = blockIdx.x;
  int tid = threadIdx.x;
  float4 av = *(const float4*)&a[row * D_MODEL + tid * 4];
  float4 rv = *(const float4*)&r[row * D_MODEL + tid * 4];
  float val[4] = {av.x + rv.x, av.y + rv.y, av.z + rv.z, av.w + rv.w};
  float sum = val[0] + val[1] + val[2] + val[3];
  float ss  = val[0] * val[0] + val[1] * val[1] + val[2] * val[2] + val[3] * val[3];
  block_reduce2(sum, ss, red);
  float mu  = sum * (1.f / D_MODEL);
  float var = ss * (1.f / D_MODEL) - mu * mu;
  float inv = rsqrtf(var + LN_EPS);
  float4 gv = *(const float4*)&gamma[tid * 4];
  float4 bv = *(const float4*)&beta[tid * 4];
  float o[4];
  o[0] = (val[0] - mu) * inv * gv.x + bv.x;
  o[1] = (val[1] - mu) * inv * gv.y + bv.y;
  o[2] = (val[2] - mu) * inv * gv.z + bv.z;
  o[3] = (val[3] - mu) * inv * gv.w + bv.w;
  *(float4*)&out[row * D_MODEL + tid * 4] = *(float4*)o;
  if (ohi) {
    ushort4 h4, l4;
    unsigned short h, l;
    bfsplit(o[0], h, l); h4.x = h; l4.x = l;
    bfsplit(o[1], h, l); h4.y = h; l4.y = l;
    bfsplit(o[2], h, l); h4.z = h; l4.z = l;
    bfsplit(o[3], h, l); h4.w = h; l4.w = l;
    *(ushort4*)&ohi[row * D_MODEL + tid * 4] = h4;
    *(ushort4*)&olo[row * D_MODEL + tid * 4] = l4;
  }
}

// ---------------------------------------------------------------------------
extern "C" void kernel_launch(void* const* d_in, const int* in_sizes, int n_in,
                              void* d_out, int out_size, void* d_ws, size_t ws_size,
                              hipStream_t stream) {
  const float* x     = (const float*)d_in[0];
  const float* W_emb = (const float*)d_in[1];
  const float* b_emb = (const float*)d_in[2];
  const float* g0    = (const float*)d_in[3];
  const float* beta0 = (const float*)d_in[4];
  const float* Wq    = (const float*)d_in[5];
  const float* bq    = (const float*)d_in[6];
  const float* Wk    = (const float*)d_in[7];
  const float* bk    = (const float*)d_in[8];
  const float* Wv    = (const float*)d_in[9];
  const float* bv    = (const float*)d_in[10];
  const float* Wo    = (const float*)d_in[11];
  const float* bo    = (const float*)d_in[12];
  const float* g1    = (const float*)d_in[13];
  const float* beta1 = (const float*)d_in[14];
  const float* W1    = (const float*)d_in[15];
  const float* b1    = (const float*)d_in[16];
  const float* W2    = (const float*)d_in[17];
  const float* b2    = (const float*)d_in[18];
  const float* g2    = (const float*)d_in[19];
  const float* beta2 = (const float*)d_in[20];
  float* out = (float*)d_out;
  char* W = (char*)d_ws;

  const int S  = 2048;
  const int BS = in_sizes[0] / FIN;       // 4096
  const int B  = BS / S;                  // 2
  const size_t MB = 1024 * 1024;
  const float qscale = 1.4426950408889634f / sqrtf((float)S);  // log2e/sqrt(S)

  // workspace layout (byte offsets; 224 MB total, aliases per liveness)
  unsigned short* wqThi = (unsigned short*)(W + 0 * MB);
  unsigned short* wqTlo = (unsigned short*)(W + 4 * MB);
  unsigned short* wkThi = (unsigned short*)(W + 8 * MB);
  unsigned short* wkTlo = (unsigned short*)(W + 12 * MB);
  unsigned short* wvThi = (unsigned short*)(W + 16 * MB);
  unsigned short* wvTlo = (unsigned short*)(W + 20 * MB);
  unsigned short* woThi = (unsigned short*)(W + 24 * MB);
  unsigned short* woTlo = (unsigned short*)(W + 28 * MB);
  unsigned short* w1Thi = (unsigned short*)(W + 32 * MB);
  unsigned short* w1Tlo = (unsigned short*)(W + 40 * MB);
  unsigned short* w2Thi = (unsigned short*)(W + 48 * MB);
  unsigned short* w2Tlo = (unsigned short*)(W + 56 * MB);
  float*          h0f   = (float*)        (W + 64 * MB);
  unsigned short* h0hi  = (unsigned short*)(W + 80 * MB);
  unsigned short* h0lo  = (unsigned short*)(W + 88 * MB);
  unsigned short* Qhi_  = (unsigned short*)(W + 96 * MB);   // [(bh)][s][dh]
  unsigned short* Qlo_  = (unsigned short*)(W + 112 * MB);
  unsigned short* Khi_  = (unsigned short*)(W + 128 * MB);
  unsigned short* Klo_  = (unsigned short*)(W + 144 * MB);
  unsigned short* Vhi_  = (unsigned short*)(W + 160 * MB);
  unsigned short* Vlo_  = (unsigned short*)(W + 176 * MB);
  unsigned short* VThi_ = (unsigned short*)(W + 192 * MB);  // [(bh)][dh][s]
  unsigned short* VTlo_ = (unsigned short*)(W + 208 * MB);
  unsigned short* ctxhi = (unsigned short*)(W + 160 * MB);  // over V (dead)
  unsigned short* ctxlo = (unsigned short*)(W + 176 * MB);
  float*          ao    = (float*)        (W + 96 * MB);    // over Q (dead)
  float*          h1f   = (float*)        (W + 112 * MB);   // over Qlo (dead)
  unsigned short* h1hi  = (unsigned short*)(W + 128 * MB);  // over Khi (dead)
  unsigned short* h1lo  = (unsigned short*)(W + 136 * MB);
  unsigned short* midhi = (unsigned short*)(W + 144 * MB);  // over Klo+ctxhi (dead)
  unsigned short* midlo = (unsigned short*)(W + 176 * MB);  // over ctxlo+VThi (dead)
  float*          f2    = (float*)        (W + 208 * MB);   // over VTlo (dead)

  // 0) weight transpose + split
  transpose_split_kernel<<<dim3(ATTF / 32, D_MODEL / 32), 256, 0, stream>>>(Wq, wqThi, wqTlo, D_MODEL, ATTF);
  transpose_split_kernel<<<dim3(ATTF / 32, D_MODEL / 32), 256, 0, stream>>>(Wk, wkThi, wkTlo, D_MODEL, ATTF);
  transpose_split_kernel<<<dim3(ATTF / 32, D_MODEL / 32), 256, 0, stream>>>(Wv, wvThi, wvTlo, D_MODEL, ATTF);
  transpose_split_kernel<<<dim3(D_MODEL / 32, ATTF / 32), 256, 0, stream>>>(Wo, woThi, woTlo, ATTF, D_MODEL);
  transpose_split_kernel<<<dim3(4 * D_MODEL / 32, D_MODEL / 32), 256, 0, stream>>>(W1, w1Thi, w1Tlo, D_MODEL, 4 * D_MODEL);
  transpose_split_kernel<<<dim3(D_MODEL / 32, 4 * D_MODEL / 32), 256, 0, stream>>>(W2, w2Thi, w2Tlo, 4 * D_MODEL, D_MODEL);

  // 1) embed + timing + LN0
  embed_ln_kernel<<<BS, 256, 0, stream>>>(x, W_emb, b_emb, g0, beta0, h0f, h0hi, h0lo, S);

  // 2) q,k,v projections -> head-major bf16 hi/lo (Q pre-scaled, exp2 domain)
  gemm_bf16s_kernel<<<dim3(ATTF / 128, BS / 128), 256, 0, stream>>>(
      h0hi, h0lo, wqThi, wqTlo, bq, nullptr, Qhi_, Qlo_, BS, ATTF, D_MODEL, 0, 1, 1, qscale);
  gemm_bf16s_kernel<<<dim3(ATTF / 128, BS / 128), 256, 0, stream>>>(
      h0hi, h0lo, wkThi, wkTlo, bk, nullptr, Khi_, Klo_, BS, ATTF, D_MODEL, 0, 1, 1, 1.f);
  gemm_bf16s_kernel<<<dim3(ATTF / 128, BS / 128), 256, 0, stream>>>(
      h0hi, h0lo, wvThi, wvTlo, bv, nullptr, Vhi_, Vlo_, BS, ATTF, D_MODEL, 0, 1, 1, 1.f);

  // 3) V transpose per (b,h)
  transpose_v_kernel<<<dim3(S / 32, DHEAD / 32, B * NHEADS), 256, 0, stream>>>(
      Vhi_, Vlo_, VThi_, VTlo_, S);

  // 4) MFMA causal attention (8-wave, QBLK=128) -> ctx hi/lo [bs][2048]
  attn_mfma_kernel<<<dim3(S / 128, B * NHEADS), 512, 0, stream>>>(
      Qhi_, Qlo_, Khi_, Klo_, VThi_, VTlo_, ctxhi, ctxlo, S);

  // 5) output projection -> ao fp32
  gemm_bf16s_kernel<<<dim3(D_MODEL / 128, BS / 128), 256, 0, stream>>>(
      ctxhi, ctxlo, woThi, woTlo, bo, ao, nullptr, nullptr, BS, D_MODEL, ATTF, 0, 0, 0, 1.f);

  // 6) h1 = LN(h0 + ao), + hi/lo split
  resid_ln_kernel<<<BS, 256, 0, stream>>>(h0f, ao, g1, beta1, h1f, h1hi, h1lo);

  // 7) FFN up (relu) -> mid hi/lo
  gemm_bf16s_kernel<<<dim3(4 * D_MODEL / 128, BS / 128), 256, 0, stream>>>(
      h1hi, h1lo, w1Thi, w1Tlo, b1, nullptr, midhi, midlo, BS, 4 * D_MODEL, D_MODEL, 1, 1, 0, 1.f);

  // 8) FFN down -> f2 fp32
  gemm_bf16s_kernel<<<dim3(D_MODEL / 128, BS / 128), 256, 0, stream>>>(
      midhi, midlo, w2Thi, w2Tlo, b2, f2, nullptr, nullptr, BS, D_MODEL, 4 * D_MODEL, 0, 0, 0, 1.f);

  // 9) out = LN(h1 + f2)
  resid_ln_kernel<<<BS, 256, 0, stream>>>(h1f, f2, g2, beta2, out, nullptr, nullptr);
}

// Round 9
// 1176.607 us; speedup vs baseline: 3.8163x; 1.0435x over previous
//
#include <hip/hip_runtime.h>
#include <hip/hip_bf16.h>
#include <math.h>

// FFNN_encoder, round 9.
// R9 (attn only): T14 async-STAGE split — next K/V tile loaded into regs
// before compute, ds_write after the barrier (HBM latency hidden under
// MFMA+softmax). T13 defer-max (THR=8 exp2-domain) — skip shfl-max chain and
// rescale when __all(max growth <= 8); P bounded by 2^8, fp32 accum safe.
// GEMMs/LN/transposes unchanged from measured R8.

#define D_MODEL 1024
#define NHEADS  16
#define DHEAD   128
#define ATTF    2048
#define FIN     64
#define LN_EPS  1e-3f

typedef __attribute__((ext_vector_type(8))) short short8;
typedef __attribute__((ext_vector_type(4))) float f32x4;

#define GLOAD_LDS(gp, lp) \
  __builtin_amdgcn_global_load_lds((const __attribute__((address_space(1))) void*)(gp), \
                                   (__attribute__((address_space(3))) void*)(lp), 16, 0, 0)

// bf16 RNE conversion (bit-level, finite values only)
__device__ __forceinline__ unsigned short f2bf(float f) {
  unsigned int x = __float_as_uint(f);
  return (unsigned short)((x + 0x7fffu + ((x >> 16) & 1u)) >> 16);
}
__device__ __forceinline__ float bf2f(unsigned short u) {
  return __uint_as_float(((unsigned int)u) << 16);
}
__device__ __forceinline__ void bfsplit(float f, unsigned short& hi, unsigned short& lo) {
  hi = f2bf(f);
  lo = f2bf(f - bf2f(hi));
}

// ---------------------------------------------------------------------------
__device__ __forceinline__ void block_reduce2(float& a, float& b, float* sbuf) {
#pragma unroll
  for (int off = 32; off > 0; off >>= 1) {
    a += __shfl_xor(a, off);
    b += __shfl_xor(b, off);
  }
  int lane = threadIdx.x & 63;
  int w    = threadIdx.x >> 6;
  if (lane == 0) { sbuf[w] = a; sbuf[4 + w] = b; }
  __syncthreads();
  a = sbuf[0] + sbuf[1] + sbuf[2] + sbuf[3];
  b = sbuf[4] + sbuf[5] + sbuf[6] + sbuf[7];
}

// ---------------------------------------------------------------------------
// Weight transpose + bf16 hi/lo split.  W[K][N] fp32 -> T[N][K] bf16 x2
__global__ __launch_bounds__(256) void transpose_split_kernel(
    const float* __restrict__ W, unsigned short* __restrict__ Thi,
    unsigned short* __restrict__ Tlo, int K, int N)
{
  __shared__ float ls[32][33];
  int n0 = blockIdx.x * 32, k0 = blockIdx.y * 32;
  int t = threadIdx.x;
  int kl = t >> 3, nl4 = (t & 7) * 4;
  float4 v = *(const float4*)&W[(size_t)(k0 + kl) * N + n0 + nl4];
  ls[kl][nl4 + 0] = v.x; ls[kl][nl4 + 1] = v.y;
  ls[kl][nl4 + 2] = v.z; ls[kl][nl4 + 3] = v.w;
  __syncthreads();
  int nl = t >> 3, kl4 = (t & 7) * 4;
  ushort4 h4, l4;
  unsigned short h, l;
  bfsplit(ls[kl4 + 0][nl], h, l); h4.x = h; l4.x = l;
  bfsplit(ls[kl4 + 1][nl], h, l); h4.y = h; l4.y = l;
  bfsplit(ls[kl4 + 2][nl], h, l); h4.z = h; l4.z = l;
  bfsplit(ls[kl4 + 3][nl], h, l); h4.w = h; l4.w = l;
  size_t o = (size_t)(n0 + nl) * K + k0 + kl4;
  *(ushort4*)&Thi[o] = h4;
  *(ushort4*)&Tlo[o] = l4;
}

// ---------------------------------------------------------------------------
// V transpose per (b,h): V[(bh)][s][dh] -> VT[(bh)][dh][s], bf16 hi/lo
__global__ __launch_bounds__(256) void transpose_v_kernel(
    const unsigned short* __restrict__ Vhi, const unsigned short* __restrict__ Vlo,
    unsigned short* __restrict__ VThi, unsigned short* __restrict__ VTlo, int S)
{
  __shared__ unsigned short ls[32][36];
  int s0 = blockIdx.x * 32, d0 = blockIdx.y * 32;
  int bh = blockIdx.z;
  size_t base = (size_t)bh * S * DHEAD;
  int t = threadIdx.x;
  int sl = t >> 3, c4 = (t & 7) * 4;
#pragma unroll
  for (int buf = 0; buf < 2; ++buf) {
    const unsigned short* src = buf ? Vlo : Vhi;
    unsigned short* dst = buf ? VTlo : VThi;
    ushort4 v = *(const ushort4*)&src[base + (size_t)(s0 + sl) * DHEAD + d0 + c4];
    __syncthreads();   // protect ls from previous buf's readers
    ls[sl][c4 + 0] = v.x; ls[sl][c4 + 1] = v.y;
    ls[sl][c4 + 2] = v.z; ls[sl][c4 + 3] = v.w;
    __syncthreads();
    ushort4 o;
    o.x = ls[c4 + 0][sl]; o.y = ls[c4 + 1][sl];
    o.z = ls[c4 + 2][sl]; o.w = ls[c4 + 3][sl];
    *(ushort4*)&dst[base + (size_t)(d0 + sl) * S + s0 + c4] = o;
  }
}

// ---------------------------------------------------------------------------
// Embedding dense(64->1024) + relu + timing signal + LayerNorm.
__global__ __launch_bounds__(256) void embed_ln_kernel(
    const float* __restrict__ x, const float* __restrict__ Wemb,
    const float* __restrict__ bemb, const float* __restrict__ g0,
    const float* __restrict__ beta0, float* __restrict__ h0,
    unsigned short* __restrict__ h0hi, unsigned short* __restrict__ h0lo, int S)
{
  __shared__ __align__(16) float xs[FIN];
  __shared__ float red[8];
  int row = blockIdx.x;
  int s   = row % S;
  int tid = threadIdx.x;
  if (tid < FIN / 4)
    *(float4*)&xs[tid * 4] = *(const float4*)&x[(size_t)row * FIN + tid * 4];
  __syncthreads();

  float acc[4];
#pragma unroll
  for (int j = 0; j < 4; ++j) acc[j] = bemb[tid + 256 * j];
#pragma unroll 8
  for (int f = 0; f < FIN; ++f) {
    float xf = xs[f];
    const float* wrow = Wemb + (size_t)f * D_MODEL + tid;
#pragma unroll
    for (int j = 0; j < 4; ++j) acc[j] = fmaf(xf, wrow[256 * j], acc[j]);
  }

  const float log_inc = 0.0180241487920284f;  // ln(10000)/511
  float ps = (float)s;
  float val[4];
#pragma unroll
  for (int j = 0; j < 4; ++j) {
    int d = tid + 256 * j;
    float ts;
    if (d < 512) ts = sinf(ps * expf(-(float)d * log_inc));
    else         ts = cosf(ps * expf(-(float)(d - 512) * log_inc));
    val[j] = fmaxf(acc[j], 0.f) + ts;
  }

  float sum = 0.f, ss = 0.f;
#pragma unroll
  for (int j = 0; j < 4; ++j) { sum += val[j]; ss += val[j] * val[j]; }
  block_reduce2(sum, ss, red);
  float mu  = sum * (1.f / D_MODEL);
  float var = ss * (1.f / D_MODEL) - mu * mu;
  float inv = rsqrtf(var + LN_EPS);
#pragma unroll
  for (int j = 0; j < 4; ++j) {
    int d = tid + 256 * j;
    float v = (val[j] - mu) * inv * g0[d] + beta0[d];
    size_t idx = (size_t)row * D_MODEL + d;
    h0[idx] = v;
    unsigned short h, l;
    bfsplit(v, h, l);
    h0hi[idx] = h; h0lo[idx] = l;
  }
}

// ---------------------------------------------------------------------------
// Split-bf16 MFMA GEMM.  C[M,N] = act((A[M,K] @ B^T[N,K] + bias) * oscale)
// out modes: split=0 -> fp32 C; split=1 -> bf16 hi/lo. headmode=1 additionally
// permutes [b*S+s][h*DH+dh] -> [(b*H+h)*S+s][dh]  (S=2048, H=16, DH=128).
__global__ __launch_bounds__(256) void gemm_bf16s_kernel(
    const unsigned short* __restrict__ Ahi, const unsigned short* __restrict__ Alo,
    const unsigned short* __restrict__ Bhi, const unsigned short* __restrict__ Blo,
    const float* __restrict__ bias, float* __restrict__ C,
    unsigned short* __restrict__ Chi, unsigned short* __restrict__ Clo,
    int M, int N, int K, int relu, int split, int headmode, float oscale)
{
  __shared__ unsigned short lds[4][128][32];   // Ahi, Alo, Bhi, Blo
  int tid = threadIdx.x;
  int w = tid >> 6, lane = tid & 63;
  int m0 = blockIdx.y * 128, n0 = blockIdx.x * 128;
  int wm = (w >> 1) * 64, wn = (w & 1) * 64;
  int fl = lane & 15, fh = lane >> 4;

  f32x4 acc[4][4];
#pragma unroll
  for (int i = 0; i < 4; ++i)
#pragma unroll
    for (int j = 0; j < 4; ++j)
#pragma unroll
      for (int r = 0; r < 4; ++r) acc[i][j][r] = 0.f;

  const unsigned short* gbase[4];
  gbase[0] = Ahi + (size_t)m0 * K;
  gbase[1] = Alo + (size_t)m0 * K;
  gbase[2] = Bhi + (size_t)n0 * K;
  gbase[3] = Blo + (size_t)n0 * K;
  int srow = w * 16 + (lane >> 2);
  int scol = (lane & 3) * 8;

  for (int kt = 0; kt < K; kt += 32) {
    __syncthreads();
#pragma unroll
    for (int t = 0; t < 4; ++t) {
#pragma unroll
      for (int r = 0; r < 2; ++r) {
        const unsigned short* src = gbase[t] + (size_t)(r * 64 + srow) * K + kt + scol;
        GLOAD_LDS(src, &lds[t][r * 64 + w * 16][0]);
      }
    }
    __syncthreads();

    short8 ah[4], al[4];
#pragma unroll
    for (int i = 0; i < 4; ++i) {
      ah[i] = *(const short8*)&lds[0][wm + i * 16 + fl][fh * 8];
      al[i] = *(const short8*)&lds[1][wm + i * 16 + fl][fh * 8];
    }
#pragma unroll
    for (int j = 0; j < 4; ++j) {
      short8 bh = *(const short8*)&lds[2][wn + j * 16 + fl][fh * 8];
      short8 bl = *(const short8*)&lds[3][wn + j * 16 + fl][fh * 8];
#pragma unroll
      for (int i = 0; i < 4; ++i) {
        acc[i][j] = __builtin_amdgcn_mfma_f32_16x16x32_bf16(ah[i], bh, acc[i][j], 0, 0, 0);
        acc[i][j] = __builtin_amdgcn_mfma_f32_16x16x32_bf16(ah[i], bl, acc[i][j], 0, 0, 0);
        acc[i][j] = __builtin_amdgcn_mfma_f32_16x16x32_bf16(al[i], bh, acc[i][j], 0, 0, 0);
      }
    }
  }

#pragma unroll
  for (int j = 0; j < 4; ++j) {
    int gc = n0 + wn + j * 16 + fl;
    float bv = bias[gc];
#pragma unroll
    for (int i = 0; i < 4; ++i) {
      int gr = m0 + wm + i * 16 + fh * 4;
#pragma unroll
      for (int r = 0; r < 4; ++r) {
        float v = (acc[i][j][r] + bv) * oscale;
        if (relu) v = fmaxf(v, 0.f);
        if (split) {
          unsigned short h, l;
          bfsplit(v, h, l);
          size_t o;
          if (headmode) {
            int row = gr + r;   // b*2048 + s
            o = (((size_t)(row >> 11) * NHEADS + (gc >> 7)) * 2048 + (row & 2047)) * DHEAD + (gc & 127);
          } else {
            o = (size_t)(gr + r) * N + gc;
          }
          Chi[o] = h; Clo[o] = l;
        } else {
          C[(size_t)(gr + r) * N + gc] = v;
        }
      }
    }
  }
}

// ---------------------------------------------------------------------------
// MFMA causal flash attention. grid=(S/128, B*H), heavy q-tiles first.
// 512 threads = 8 waves; wave w owns q rows [qb+16w, qb+16w+16), QBLK=128.
// R9: async-STAGE split (next tile in regs during compute, ds_write after
// barrier) + defer-max (skip shfl-max+rescale when max growth <= 8 in exp2
// domain; P bounded by 2^8). Frag conventions match the verified GEMM:
// C row=(lane>>4)*4+r, col=lane&15.
__global__ __launch_bounds__(512) void attn_mfma_kernel(
    const unsigned short* __restrict__ Qhi, const unsigned short* __restrict__ Qlo,
    const unsigned short* __restrict__ Khi, const unsigned short* __restrict__ Klo,
    const unsigned short* __restrict__ VThi, const unsigned short* __restrict__ VTlo,
    unsigned short* __restrict__ Ohi, unsigned short* __restrict__ Olo, int S)
{
  __shared__ unsigned short Kh[32][136], Kl[32][136];     // [k][dh], +8 pad
  __shared__ unsigned short Vh[128][40], Vl[128][40];     // [dh][k], +8 pad
  __shared__ unsigned short Ph[8][16][40], Pl[8][16][40]; // per-wave P

  int bh = blockIdx.y;
  int qb = ((int)gridDim.x - 1 - (int)blockIdx.x) * 128;  // heavy first
  int tid = threadIdx.x, w = tid >> 6, lane = tid & 63;
  int fl = lane & 15, fh = lane >> 4;
  size_t hb = (size_t)bh * S * DHEAD;

  // Q A-frags: row=fl, k-chunk=fh*8, 4 dh-chunks, hi/lo
  short8 qh[4], ql[4];
  {
    size_t qoff = hb + (size_t)(qb + w * 16 + fl) * DHEAD + fh * 8;
#pragma unroll
    for (int c = 0; c < 4; ++c) {
      qh[c] = *(const short8*)&Qhi[qoff + c * 32];
      ql[c] = *(const short8*)&Qlo[qoff + c * 32];
    }
  }

  f32x4 acc[8];
#pragma unroll
  for (int t = 0; t < 8; ++t)
#pragma unroll
    for (int r = 0; r < 4; ++r) acc[t][r] = 0.f;
  float m[4] = {-1e38f, -1e38f, -1e38f, -1e38f};
  float l[4] = {0.f, 0.f, 0.f, 0.f};

  const int qmin = qb + w * 16;
  const int qmax = qmin + 15;
  const int nkt = (qb + 128) >> 5;

  // staging indices (512 threads, one pass per buffer)
  const int kr = tid >> 4, kc = (tid & 15) * 8;   // K: 32 rows x 128 cols
  const int vr = tid >> 2, vc = (tid & 3) * 8;    // V: 128 rows x 32 cols

  // prologue: stage tile 0 (latency exposed once per block)
  {
    size_t g = hb + (size_t)kr * DHEAD + kc;
    *(short8*)&Kh[kr][kc] = *(const short8*)&Khi[g];
    *(short8*)&Kl[kr][kc] = *(const short8*)&Klo[g];
    size_t gv = hb + (size_t)vr * S + vc;
    *(short8*)&Vh[vr][vc] = *(const short8*)&VThi[gv];
    *(short8*)&Vl[vr][vc] = *(const short8*)&VTlo[gv];
  }
  __syncthreads();

  for (int kt = 0; kt < nkt; ++kt) {
    const int k0 = kt << 5;

    // T14: issue next-tile global loads BEFORE compute (latency hides under
    // MFMA+softmax; consumed by ds_write after the barrier)
    short8 rkh, rkl, rvh, rvl;
    const bool have_next = (kt + 1 < nkt);
    if (have_next) {
      const int kn = k0 + 32;
      size_t g = hb + (size_t)(kn + kr) * DHEAD + kc;
      rkh = *(const short8*)&Khi[g];
      rkl = *(const short8*)&Klo[g];
      size_t gv = hb + (size_t)vr * S + kn + vc;
      rvh = *(const short8*)&VThi[gv];
      rvl = *(const short8*)&VTlo[gv];
    }

    if (k0 <= qmax) {   // wave-uniform; fully-masked waves skip compute only
      // QK^T: 2 k-subtiles x 4 dh-chunks x 3 mfma
      f32x4 s0 = {0.f, 0.f, 0.f, 0.f}, s1 = {0.f, 0.f, 0.f, 0.f};
      __builtin_amdgcn_s_setprio(1);
#pragma unroll
      for (int c = 0; c < 4; ++c) {
        short8 k0h = *(const short8*)&Kh[fl][c * 32 + fh * 8];
        short8 k0l = *(const short8*)&Kl[fl][c * 32 + fh * 8];
        short8 k1h = *(const short8*)&Kh[16 + fl][c * 32 + fh * 8];
        short8 k1l = *(const short8*)&Kl[16 + fl][c * 32 + fh * 8];
        s0 = __builtin_amdgcn_mfma_f32_16x16x32_bf16(qh[c], k0h, s0, 0, 0, 0);
        s0 = __builtin_amdgcn_mfma_f32_16x16x32_bf16(qh[c], k0l, s0, 0, 0, 0);
        s0 = __builtin_amdgcn_mfma_f32_16x16x32_bf16(ql[c], k0h, s0, 0, 0, 0);
        s1 = __builtin_amdgcn_mfma_f32_16x16x32_bf16(qh[c], k1h, s1, 0, 0, 0);
        s1 = __builtin_amdgcn_mfma_f32_16x16x32_bf16(qh[c], k1l, s1, 0, 0, 0);
        s1 = __builtin_amdgcn_mfma_f32_16x16x32_bf16(ql[c], k1h, s1, 0, 0, 0);
      }
      __builtin_amdgcn_s_setprio(0);
      if (k0 + 31 > qmin) {     // edge tile: apply causal mask
#pragma unroll
        for (int r = 0; r < 4; ++r) {
          int q = qmin + fh * 4 + r;
          if (k0 + fl > q)      s0[r] = -1e38f;
          if (k0 + 16 + fl > q) s1[r] = -1e38f;
        }
      }

      // T13 defer-max: full rescale only when max grows by > 8 (exp2 domain)
      float d = -1e38f;
#pragma unroll
      for (int r = 0; r < 4; ++r)
        d = fmaxf(d, fmaxf(s0[r], s1[r]) - m[r]);
      if (!__all(d <= 8.f)) {
#pragma unroll
        for (int r = 0; r < 4; ++r) {
          float tm = fmaxf(s0[r], s1[r]);
          tm = fmaxf(tm, __shfl_xor(tm, 1));
          tm = fmaxf(tm, __shfl_xor(tm, 2));
          tm = fmaxf(tm, __shfl_xor(tm, 4));
          tm = fmaxf(tm, __shfl_xor(tm, 8));
          float mn = fmaxf(m[r], tm);
          float so = exp2f(m[r] - mn);
          m[r] = mn;
          l[r] *= so;
#pragma unroll
          for (int t = 0; t < 8; ++t) acc[t][r] *= so;
        }
      }

#pragma unroll
      for (int r = 0; r < 4; ++r) {
        float p0 = exp2f(s0[r] - m[r]);
        float p1 = exp2f(s1[r] - m[r]);
        unsigned short hh, ll;
        bfsplit(p0, hh, ll);
        Ph[w][fh * 4 + r][fl] = hh;      Pl[w][fh * 4 + r][fl] = ll;
        bfsplit(p1, hh, ll);
        Ph[w][fh * 4 + r][16 + fl] = hh; Pl[w][fh * 4 + r][16 + fl] = ll;
        float rs = p0 + p1;
        rs += __shfl_xor(rs, 1);
        rs += __shfl_xor(rs, 2);
        rs += __shfl_xor(rs, 4);
        rs += __shfl_xor(rs, 8);
        l[r] += rs;
      }

      // PV: A = P (same-wave LDS round-trip), B = V^T frags
      short8 pah = *(const short8*)&Ph[w][fl][fh * 8];
      short8 pal = *(const short8*)&Pl[w][fl][fh * 8];
      __builtin_amdgcn_s_setprio(1);
#pragma unroll
      for (int t = 0; t < 8; ++t) {
        short8 vth = *(const short8*)&Vh[t * 16 + fl][fh * 8];
        short8 vtl = *(const short8*)&Vl[t * 16 + fl][fh * 8];
        acc[t] = __builtin_amdgcn_mfma_f32_16x16x32_bf16(pah, vth, acc[t], 0, 0, 0);
        acc[t] = __builtin_amdgcn_mfma_f32_16x16x32_bf16(pah, vtl, acc[t], 0, 0, 0);
        acc[t] = __builtin_amdgcn_mfma_f32_16x16x32_bf16(pal, vth, acc[t], 0, 0, 0);
      }
      __builtin_amdgcn_s_setprio(0);
    }

    __syncthreads();            // all waves done reading current tile
    if (have_next) {            // T14: write prefetched tile (vmcnt inserted)
      *(short8*)&Kh[kr][kc] = rkh;
      *(short8*)&Kl[kr][kc] = rkl;
      *(short8*)&Vh[vr][vc] = rvh;
      *(short8*)&Vl[vr][vc] = rvl;
    }
    __syncthreads();            // next tile ready
  }

  int b_ = bh >> 4, h_ = bh & 15;
  float inv[4];
#pragma unroll
  for (int r = 0; r < 4; ++r) inv[r] = 1.f / l[r];
#pragma unroll
  for (int t = 0; t < 8; ++t) {
#pragma unroll
    for (int r = 0; r < 4; ++r) {
      float v = acc[t][r] * inv[r];
      size_t o = ((size_t)b_ * S + qb + w * 16 + fh * 4 + r) * ATTF + h_ * DHEAD + t * 16 + fl;
      unsigned short hh, ll;
      bfsplit(v, hh, ll);
      Ohi[o] = hh; Olo[o] = ll;
    }
  }
}

// ---------------------------------------------------------------------------
// out = LN(a + r); optionally also bf16 hi/lo split of out.
__global__ __launch_bounds__(256) void resid_ln_kernel(
    const float* __restrict__ a, const float* __restrict__ r,
    const float* __restrict__ gamma, const float* __restrict__ beta,
    float* __restrict__ out, unsigned short* __restrict__ ohi,
    unsigned short* __restrict__ olo)
{
  __shared__ float red[8];
  size_t row = blockIdx.x;
  int tid = threadIdx.x;
  float4 av = *(const float4*)&a[row * D_MODEL + tid * 4];
  float4 rv = *(const float4*)&r[row * D_MODEL + tid * 4];
  float val[4] = {av.x + rv.x, av.y + rv.y, av.z + rv.z, av.w + rv.w};
  float sum = val[0] + val[1] + val[2] + val[3];
  float ss  = val[0] * val[0] + val[1] * val[1] + val[2] * val[2] + val[3] * val[3];
  block_reduce2(sum, ss, red);
  float mu  = sum * (1.f / D_MODEL);
  float var = ss * (1.f / D_MODEL) - mu * mu;
  float inv = rsqrtf(var + LN_EPS);
  float4 gv = *(const float4*)&gamma[tid * 4];
  float4 bv = *(const float4*)&beta[tid * 4];
  float o[4];
  o[0] = (val[0] - mu) * inv * gv.x + bv.x;
  o[1] = (val[1] - mu) * inv * gv.y + bv.y;
  o[2] = (val[2] - mu) * inv * gv.z + bv.z;
  o[3] = (val[3] - mu) * inv * gv.w + bv.w;
  *(float4*)&out[row * D_MODEL + tid * 4] = *(float4*)o;
  if (ohi) {
    ushort4 h4, l4;
    unsigned short h, l;
    bfsplit(o[0], h, l); h4.x = h; l4.x = l;
    bfsplit(o[1], h, l); h4.y = h; l4.y = l;
    bfsplit(o[2], h, l); h4.z = h; l4.z = l;
    bfsplit(o[3], h, l); h4.w = h; l4.w = l;
    *(ushort4*)&ohi[row * D_MODEL + tid * 4] = h4;
    *(ushort4*)&olo[row * D_MODEL + tid * 4] = l4;
  }
}

// ---------------------------------------------------------------------------
extern "C" void kernel_launch(void* const* d_in, const int* in_sizes, int n_in,
                              void* d_out, int out_size, void* d_ws, size_t ws_size,
                              hipStream_t stream) {
  const float* x     = (const float*)d_in[0];
  const float* W_emb = (const float*)d_in[1];
  const float* b_emb = (const float*)d_in[2];
  const float* g0    = (const float*)d_in[3];
  const float* beta0 = (const float*)d_in[4];
  const float* Wq    = (const float*)d_in[5];
  const float* bq    = (const float*)d_in[6];
  const float* Wk    = (const float*)d_in[7];
  const float* bk    = (const float*)d_in[8];
  const float* Wv    = (const float*)d_in[9];
  const float* bv    = (const float*)d_in[10];
  const float* Wo    = (const float*)d_in[11];
  const float* bo    = (const float*)d_in[12];
  const float* g1    = (const float*)d_in[13];
  const float* beta1 = (const float*)d_in[14];
  const float* W1    = (const float*)d_in[15];
  const float* b1    = (const float*)d_in[16];
  const float* W2    = (const float*)d_in[17];
  const float* b2    = (const float*)d_in[18];
  const float* g2    = (const float*)d_in[19];
  const float* beta2 = (const float*)d_in[20];
  float* out = (float*)d_out;
  char* W = (char*)d_ws;

  const int S  = 2048;
  const int BS = in_sizes[0] / FIN;       // 4096
  const int B  = BS / S;                  // 2
  const size_t MB = 1024 * 1024;
  const float qscale = 1.4426950408889634f / sqrtf((float)S);  // log2e/sqrt(S)

  // workspace layout (byte offsets; 224 MB total, aliases per liveness)
  unsigned short* wqThi = (unsigned short*)(W + 0 * MB);
  unsigned short* wqTlo = (unsigned short*)(W + 4 * MB);
  unsigned short* wkThi = (unsigned short*)(W + 8 * MB);
  unsigned short* wkTlo = (unsigned short*)(W + 12 * MB);
  unsigned short* wvThi = (unsigned short*)(W + 16 * MB);
  unsigned short* wvTlo = (unsigned short*)(W + 20 * MB);
  unsigned short* woThi = (unsigned short*)(W + 24 * MB);
  unsigned short* woTlo = (unsigned short*)(W + 28 * MB);
  unsigned short* w1Thi = (unsigned short*)(W + 32 * MB);
  unsigned short* w1Tlo = (unsigned short*)(W + 40 * MB);
  unsigned short* w2Thi = (unsigned short*)(W + 48 * MB);
  unsigned short* w2Tlo = (unsigned short*)(W + 56 * MB);
  float*          h0f   = (float*)        (W + 64 * MB);
  unsigned short* h0hi  = (unsigned short*)(W + 80 * MB);
  unsigned short* h0lo  = (unsigned short*)(W + 88 * MB);
  unsigned short* Qhi_  = (unsigned short*)(W + 96 * MB);   // [(bh)][s][dh]
  unsigned short* Qlo_  = (unsigned short*)(W + 112 * MB);
  unsigned short* Khi_  = (unsigned short*)(W + 128 * MB);
  unsigned short* Klo_  = (unsigned short*)(W + 144 * MB);
  unsigned short* Vhi_  = (unsigned short*)(W + 160 * MB);
  unsigned short* Vlo_  = (unsigned short*)(W + 176 * MB);
  unsigned short* VThi_ = (unsigned short*)(W + 192 * MB);  // [(bh)][dh][s]
  unsigned short* VTlo_ = (unsigned short*)(W + 208 * MB);
  unsigned short* ctxhi = (unsigned short*)(W + 160 * MB);  // over V (dead)
  unsigned short* ctxlo = (unsigned short*)(W + 176 * MB);
  float*          ao    = (float*)        (W + 96 * MB);    // over Q (dead)
  float*          h1f   = (float*)        (W + 112 * MB);   // over Qlo (dead)
  unsigned short* h1hi  = (unsigned short*)(W + 128 * MB);  // over Khi (dead)
  unsigned short* h1lo  = (unsigned short*)(W + 136 * MB);
  unsigned short* midhi = (unsigned short*)(W + 144 * MB);  // over Klo+ctxhi (dead)
  unsigned short* midlo = (unsigned short*)(W + 176 * MB);  // over ctxlo+VThi (dead)
  float*          f2    = (float*)        (W + 208 * MB);   // over VTlo (dead)

  // 0) weight transpose + split
  transpose_split_kernel<<<dim3(ATTF / 32, D_MODEL / 32), 256, 0, stream>>>(Wq, wqThi, wqTlo, D_MODEL, ATTF);
  transpose_split_kernel<<<dim3(ATTF / 32, D_MODEL / 32), 256, 0, stream>>>(Wk, wkThi, wkTlo, D_MODEL, ATTF);
  transpose_split_kernel<<<dim3(ATTF / 32, D_MODEL / 32), 256, 0, stream>>>(Wv, wvThi, wvTlo, D_MODEL, ATTF);
  transpose_split_kernel<<<dim3(D_MODEL / 32, ATTF / 32), 256, 0, stream>>>(Wo, woThi, woTlo, ATTF, D_MODEL);
  transpose_split_kernel<<<dim3(4 * D_MODEL / 32, D_MODEL / 32), 256, 0, stream>>>(W1, w1Thi, w1Tlo, D_MODEL, 4 * D_MODEL);
  transpose_split_kernel<<<dim3(D_MODEL / 32, 4 * D_MODEL / 32), 256, 0, stream>>>(W2, w2Thi, w2Tlo, 4 * D_MODEL, D_MODEL);

  // 1) embed + timing + LN0
  embed_ln_kernel<<<BS, 256, 0, stream>>>(x, W_emb, b_emb, g0, beta0, h0f, h0hi, h0lo, S);

  // 2) q,k,v projections -> head-major bf16 hi/lo (Q pre-scaled, exp2 domain)
  gemm_bf16s_kernel<<<dim3(ATTF / 128, BS / 128), 256, 0, stream>>>(
      h0hi, h0lo, wqThi, wqTlo, bq, nullptr, Qhi_, Qlo_, BS, ATTF, D_MODEL, 0, 1, 1, qscale);
  gemm_bf16s_kernel<<<dim3(ATTF / 128, BS / 128), 256, 0, stream>>>(
      h0hi, h0lo, wkThi, wkTlo, bk, nullptr, Khi_, Klo_, BS, ATTF, D_MODEL, 0, 1, 1, 1.f);
  gemm_bf16s_kernel<<<dim3(ATTF / 128, BS / 128), 256, 0, stream>>>(
      h0hi, h0lo, wvThi, wvTlo, bv, nullptr, Vhi_, Vlo_, BS, ATTF, D_MODEL, 0, 1, 1, 1.f);

  // 3) V transpose per (b,h)
  transpose_v_kernel<<<dim3(S / 32, DHEAD / 32, B * NHEADS), 256, 0, stream>>>(
      Vhi_, Vlo_, VThi_, VTlo_, S);

  // 4) MFMA causal attention (8-wave, QBLK=128, async-stage) -> ctx hi/lo
  attn_mfma_kernel<<<dim3(S / 128, B * NHEADS), 512, 0, stream>>>(
      Qhi_, Qlo_, Khi_, Klo_, VThi_, VTlo_, ctxhi, ctxlo, S);

  // 5) output projection -> ao fp32
  gemm_bf16s_kernel<<<dim3(D_MODEL / 128, BS / 128), 256, 0, stream>>>(
      ctxhi, ctxlo, woThi, woTlo, bo, ao, nullptr, nullptr, BS, D_MODEL, ATTF, 0, 0, 0, 1.f);

  // 6) h1 = LN(h0 + ao), + hi/lo split
  resid_ln_kernel<<<BS, 256, 0, stream>>>(h0f, ao, g1, beta1, h1f, h1hi, h1lo);

  // 7) FFN up (relu) -> mid hi/lo
  gemm_bf16s_kernel<<<dim3(4 * D_MODEL / 128, BS / 128), 256, 0, stream>>>(
      h1hi, h1lo, w1Thi, w1Tlo, b1, nullptr, midhi, midlo, BS, 4 * D_MODEL, D_MODEL, 1, 1, 0, 1.f);

  // 8) FFN down -> f2 fp32
  gemm_bf16s_kernel<<<dim3(D_MODEL / 128, BS / 128), 256, 0, stream>>>(
      midhi, midlo, w2Thi, w2Tlo, b2, f2, nullptr, nullptr, BS, D_MODEL, 4 * D_MODEL, 0, 0, 0, 1.f);

  // 9) out = LN(h1 + f2)
  resid_ln_kernel<<<BS, 256, 0, stream>>>(h1f, f2, g2, beta2, out, nullptr, nullptr);
}